// Round 3
// baseline (7658.983 us; speedup 1.0000x reference)
//
#include <hip/hip_runtime.h>
#include <cmath>

#define B 64
#define S 4096
#define NI 16
#define H 128
#define G 384   // 3*H
#define F 144   // H + NI

typedef float v2f __attribute__((ext_vector_type(2)));

__device__ __forceinline__ float sigf(float x) {
    return 1.0f / (1.0f + __expf(-x));
}
// tanh(x) = (e^{2x}-1)/(e^{2x}+1); clamp keeps e finite (gate inputs are O(1))
__device__ __forceinline__ float tanh_fast(float x) {
    x = fminf(fmaxf(x, -15.0f), 15.0f);
    const float e = __expf(2.0f * x);
    return (e - 1.0f) / (e + 1.0f);
}
// 2-stage quad butterfly via DPP quad_perm: every lane of the quad gets the sum.
__device__ __forceinline__ float quad_reduce(float v) {
    int t1 = __builtin_amdgcn_mov_dpp(__float_as_int(v), 0xB1, 0xf, 0xf, true); // xor 1
    v += __int_as_float(t1);
    int t2 = __builtin_amdgcn_mov_dpp(__float_as_int(v), 0x4E, 0xf, 0xf, true); // xor 2
    v += __int_as_float(t2);
    return v;
}

// ---------------------------------------------------------------------------
// Layer 0 GRU: 64 blocks x 512 threads. Quad q owns output j = tid>>2.
// Lane m in quad: k-quarter [32m,32m+32) of rows (r=j, z=H+j, n=2H+j) plus
// x-quarter [4m,4m+4). One barrier per step; activation computed redundantly
// in-quad after DPP butterfly. launch_bounds(512,2) -> 256-VGPR budget so the
// 108 weight floats stay register-resident.
// ---------------------------------------------------------------------------
__global__ __launch_bounds__(512, 2)
void gru_layer0(const float* __restrict__ x,
                const float* __restrict__ w_ih, const float* __restrict__ w_hh,
                const float* __restrict__ b_ih, const float* __restrict__ b_hh,
                float* __restrict__ h_out)
{
    __shared__ __align__(16) float sH[2][H];

    const int b   = blockIdx.x;
    const int tid = threadIdx.x;
    const int j   = tid >> 2;
    const int m   = tid & 3;

    v2f whr[16], whz[16], whn[16];
    v2f wxr[2], wxz[2], wxn[2];
    {
        const v2f* p = (const v2f*)(w_hh + (size_t)j * H + 32 * m);
#pragma unroll
        for (int i = 0; i < 16; i++) whr[i] = p[i];
        p = (const v2f*)(w_hh + (size_t)(H + j) * H + 32 * m);
#pragma unroll
        for (int i = 0; i < 16; i++) whz[i] = p[i];
        p = (const v2f*)(w_hh + (size_t)(2 * H + j) * H + 32 * m);
#pragma unroll
        for (int i = 0; i < 16; i++) whn[i] = p[i];
        p = (const v2f*)(w_ih + (size_t)j * NI + 4 * m);
        wxr[0] = p[0]; wxr[1] = p[1];
        p = (const v2f*)(w_ih + (size_t)(H + j) * NI + 4 * m);
        wxz[0] = p[0]; wxz[1] = p[1];
        p = (const v2f*)(w_ih + (size_t)(2 * H + j) * NI + 4 * m);
        wxn[0] = p[0]; wxn[1] = p[1];
    }
    const float b_r  = b_ih[j]         + b_hh[j];
    const float b_z  = b_ih[H + j]     + b_hh[H + j];
    const float b_in = b_ih[2 * H + j];
    const float b_hn = b_hh[2 * H + j];

    const float* xb  = x + (size_t)b * S * NI + 4 * m;
    float*       hob = h_out + (size_t)b * S * H;

    float4 xc = *(const float4*)xb;            // x[0] quarter
    float4 xn = *(const float4*)(xb + NI);     // x[1] quarter
    float hprev = 0.0f;
    if (tid < H) sH[0][tid] = 0.0f;
    __syncthreads();

    for (int t = 0; t < S; t++) {
        const int cur = t & 1;
        const float4* hv = (const float4*)(&sH[cur][0]) + 8 * m;

        v2f ar = {0.f, 0.f}, az = {0.f, 0.f}, ahn = {0.f, 0.f};
#pragma unroll
        for (int i = 0; i < 8; i++) {
            const float4 h4 = hv[i];
            const v2f lo = {h4.x, h4.y}, hi = {h4.z, h4.w};
            ar  = __builtin_elementwise_fma(lo, whr[2 * i],     ar);
            ar  = __builtin_elementwise_fma(hi, whr[2 * i + 1], ar);
            az  = __builtin_elementwise_fma(lo, whz[2 * i],     az);
            az  = __builtin_elementwise_fma(hi, whz[2 * i + 1], az);
            ahn = __builtin_elementwise_fma(lo, whn[2 * i],     ahn);
            ahn = __builtin_elementwise_fma(hi, whn[2 * i + 1], ahn);
        }
        const v2f x0 = {xc.x, xc.y}, x1 = {xc.z, xc.w};
        ar = __builtin_elementwise_fma(x0, wxr[0], ar);
        ar = __builtin_elementwise_fma(x1, wxr[1], ar);
        az = __builtin_elementwise_fma(x0, wxz[0], az);
        az = __builtin_elementwise_fma(x1, wxz[1], az);
        v2f ain = {0.f, 0.f};
        ain = __builtin_elementwise_fma(x0, wxn[0], ain);
        ain = __builtin_elementwise_fma(x1, wxn[1], ain);

        const float vr  = quad_reduce(ar[0] + ar[1]);
        const float vz  = quad_reduce(az[0] + az[1]);
        const float vhn = quad_reduce(ahn[0] + ahn[1]);
        const float vin = quad_reduce(ain[0] + ain[1]);

        xc = xn;                               // advance x pipeline
        if (t + 2 < S) xn = *(const float4*)(xb + (size_t)(t + 2) * NI);

        const float r  = sigf(vr + b_r);
        const float z  = sigf(vz + b_z);
        const float n  = tanh_fast(vin + b_in + r * (vhn + b_hn));
        const float hn = n + z * (hprev - n);
        hprev = hn;
        if (m == 0) {
            sH[cur ^ 1][j] = hn;
            hob[(size_t)t * H + j] = hn;
        }
        __syncthreads();
    }
}

// ---------------------------------------------------------------------------
// Layer 1 GRU: 64 blocks x 512 threads, same quad-per-j layout. Lane holds
// quarters of 6 rows (w_ih r/z/n + w_hh r/z/n) = 192 weight floats. h0 stream
// staged into double-buffered LDS 3 steps ahead by threads tid<128; h1 state
// double-buffered; h1 overwrites h0 in place (h0[t] consumed at t-3).
// ---------------------------------------------------------------------------
__global__ __launch_bounds__(512, 2)
void gru_layer1(const float* __restrict__ w_ih, const float* __restrict__ w_hh,
                const float* __restrict__ b_ih, const float* __restrict__ b_hh,
                float* __restrict__ hbuf)
{
    __shared__ __align__(16) float sHin[2][H];
    __shared__ __align__(16) float sH1[2][H];

    const int b   = blockIdx.x;
    const int tid = threadIdx.x;
    const int j   = tid >> 2;
    const int m   = tid & 3;

    v2f wir[16], wiz[16], win[16], whr[16], whz[16], whn[16];
    {
        const v2f* p = (const v2f*)(w_ih + (size_t)j * H + 32 * m);
#pragma unroll
        for (int i = 0; i < 16; i++) wir[i] = p[i];
        p = (const v2f*)(w_ih + (size_t)(H + j) * H + 32 * m);
#pragma unroll
        for (int i = 0; i < 16; i++) wiz[i] = p[i];
        p = (const v2f*)(w_ih + (size_t)(2 * H + j) * H + 32 * m);
#pragma unroll
        for (int i = 0; i < 16; i++) win[i] = p[i];
        p = (const v2f*)(w_hh + (size_t)j * H + 32 * m);
#pragma unroll
        for (int i = 0; i < 16; i++) whr[i] = p[i];
        p = (const v2f*)(w_hh + (size_t)(H + j) * H + 32 * m);
#pragma unroll
        for (int i = 0; i < 16; i++) whz[i] = p[i];
        p = (const v2f*)(w_hh + (size_t)(2 * H + j) * H + 32 * m);
#pragma unroll
        for (int i = 0; i < 16; i++) whn[i] = p[i];
    }
    const float b_r  = b_ih[j]         + b_hh[j];
    const float b_z  = b_ih[H + j]     + b_hh[H + j];
    const float b_in = b_ih[2 * H + j];
    const float b_hn = b_hh[2 * H + j];

    float* hb = hbuf + (size_t)b * S * H;

    float pre1 = 0.f, pre2 = 0.f;
    if (tid < H) {
        sHin[0][tid] = hb[tid];          // h0[0]
        sH1[0][tid]  = 0.0f;             // h1[-1]
        pre1 = hb[H + tid];              // h0[1]
        pre2 = hb[2 * H + tid];          // h0[2]
    }
    float hprev = 0.0f;
    __syncthreads();

    for (int t = 0; t < S; t++) {
        const int cur = t & 1;
        const float4* g0 = (const float4*)(&sHin[cur][0]) + 8 * m;
        const float4* g1 = (const float4*)(&sH1[cur][0]) + 8 * m;

        v2f ar = {0.f, 0.f}, az = {0.f, 0.f}, ain = {0.f, 0.f}, ahn = {0.f, 0.f};
#pragma unroll
        for (int i = 0; i < 8; i++) {
            const float4 a4 = g0[i];
            const float4 c4 = g1[i];
            const v2f alo = {a4.x, a4.y}, ahi = {a4.z, a4.w};
            const v2f clo = {c4.x, c4.y}, chi = {c4.z, c4.w};
            ar  = __builtin_elementwise_fma(alo, wir[2 * i],     ar);
            ar  = __builtin_elementwise_fma(ahi, wir[2 * i + 1], ar);
            ar  = __builtin_elementwise_fma(clo, whr[2 * i],     ar);
            ar  = __builtin_elementwise_fma(chi, whr[2 * i + 1], ar);
            az  = __builtin_elementwise_fma(alo, wiz[2 * i],     az);
            az  = __builtin_elementwise_fma(ahi, wiz[2 * i + 1], az);
            az  = __builtin_elementwise_fma(clo, whz[2 * i],     az);
            az  = __builtin_elementwise_fma(chi, whz[2 * i + 1], az);
            ain = __builtin_elementwise_fma(alo, win[2 * i],     ain);
            ain = __builtin_elementwise_fma(ahi, win[2 * i + 1], ain);
            ahn = __builtin_elementwise_fma(clo, whn[2 * i],     ahn);
            ahn = __builtin_elementwise_fma(chi, whn[2 * i + 1], ahn);
        }
        const float vr  = quad_reduce(ar[0] + ar[1]);
        const float vz  = quad_reduce(az[0] + az[1]);
        const float vin = quad_reduce(ain[0] + ain[1]);
        const float vhn = quad_reduce(ahn[0] + ahn[1]);

        // stage h0[t+1] (in reg since step t-2) into the other buffer;
        // refill the register pipeline from global (h0[t+3]).
        if (tid < H) {
            sHin[cur ^ 1][tid] = pre1;
            pre1 = pre2;
            if (t + 3 < S) pre2 = hb[(size_t)(t + 3) * H + tid];
        }

        const float r  = sigf(vr + b_r);
        const float z  = sigf(vz + b_z);
        const float n  = tanh_fast(vin + b_in + r * (vhn + b_hn));
        const float hn = n + z * (hprev - n);
        hprev = hn;
        if (m == 0) {
            sH1[cur ^ 1][j] = hn;
            hb[(size_t)t * H + j] = hn;   // overwrite h0[t] with h1[t]
        }
        __syncthreads();
    }
}

// ---------------------------------------------------------------------------
// MLP head, batched over all B*S rows. One wave per block; lane m owns hidden
// unit m (w1 row register-resident: launch_bounds(64,2) -> 256-VGPR budget).
// ---------------------------------------------------------------------------
__global__ __launch_bounds__(64, 2)
void head_kernel(const float* __restrict__ h1, const float* __restrict__ x,
                 const float* __restrict__ w1, const float* __restrict__ b1,
                 const float* __restrict__ w2, const float* __restrict__ b2,
                 float* __restrict__ inc, int rows_per_blk)
{
    __shared__ float sC[2][F];
    const int lane = threadIdx.x;

    float wr[F];
#pragma unroll
    for (int f = 0; f < F; f++) wr[f] = w1[lane * F + f];
    const float b1v = b1[lane];
    const float w2v = w2[lane];
    const float b2v = b2[0];

    const int row0 = blockIdx.x * rows_per_blk;

    {
        const int r = row0;
        sC[0][lane]      = h1[(size_t)r * H + lane];
        sC[0][64 + lane] = h1[(size_t)r * H + 64 + lane];
        if (lane < NI) sC[0][H + lane] = x[(size_t)r * NI + lane];
    }
    __syncthreads();

    for (int i = 0; i < rows_per_blk; i++) {
        const int row = row0 + i;
        const int cur = i & 1;
        const int nxt = cur ^ 1;

        float p0 = 0.f, p1 = 0.f, p2 = 0.f;
        if (i + 1 < rows_per_blk) {
            const int rn = row + 1;
            p0 = h1[(size_t)rn * H + lane];
            p1 = h1[(size_t)rn * H + 64 + lane];
            if (lane < NI) p2 = x[(size_t)rn * NI + lane];
        }

        float acc = b1v;
#pragma unroll
        for (int f = 0; f < F; f++) acc += sC[cur][f] * wr[f];

        if (i + 1 < rows_per_blk) {
            sC[nxt][lane]      = p0;
            sC[nxt][64 + lane] = p1;
            if (lane < NI) sC[nxt][H + lane] = p2;
        }

        float v = fmaxf(acc, 0.0f) * w2v;
#pragma unroll
        for (int off = 32; off > 0; off >>= 1) v += __shfl_xor(v, off, 64);

        if (lane == 0) inc[row] = tanh_fast(v + b2v) * 0.125f;
        __syncthreads();
    }
}

// ---------------------------------------------------------------------------
// Inclusive cumsum over S per batch + initial offset. One block per batch.
// ---------------------------------------------------------------------------
__global__ __launch_bounds__(256)
void cumsum_kernel(const float* __restrict__ inc, const float* __restrict__ init,
                   float* __restrict__ out)
{
    __shared__ float sW[4];
    const int b = blockIdx.x;
    const int tid = threadIdx.x;
    const int lane = tid & 63;
    const int wid = tid >> 6;

    const float* ib = inc + (size_t)b * S;
    float v[16];
#pragma unroll
    for (int i = 0; i < 16; i++) v[i] = ib[tid * 16 + i];

    float run = 0.f;
#pragma unroll
    for (int i = 0; i < 16; i++) { run += v[i]; v[i] = run; }

    float t = run;
#pragma unroll
    for (int off = 1; off < 64; off <<= 1) {
        float u = __shfl_up(t, off, 64);
        if (lane >= off) t += u;
    }
    const float excl = t - run;
    if (lane == 63) sW[wid] = t;
    __syncthreads();

    float wo = 0.f;
#pragma unroll
    for (int w = 0; w < 4; w++) if (w < wid) wo += sW[w];

    const float prefix = wo + excl + init[0];
    float* ob = out + (size_t)b * S;
#pragma unroll
    for (int i = 0; i < 16; i++) ob[tid * 16 + i] = prefix + v[i];
}

// ---------------------------------------------------------------------------
extern "C" void kernel_launch(void* const* d_in, const int* in_sizes, int n_in,
                              void* d_out, int out_size, void* d_ws, size_t ws_size,
                              hipStream_t stream)
{
    const float* x     = (const float*)d_in[0];
    const float* w_ih0 = (const float*)d_in[1];
    const float* w_hh0 = (const float*)d_in[2];
    const float* b_ih0 = (const float*)d_in[3];
    const float* b_hh0 = (const float*)d_in[4];
    const float* w_ih1 = (const float*)d_in[5];
    const float* w_hh1 = (const float*)d_in[6];
    const float* b_ih1 = (const float*)d_in[7];
    const float* b_hh1 = (const float*)d_in[8];
    const float* w1    = (const float*)d_in[9];
    const float* b1    = (const float*)d_in[10];
    const float* w2    = (const float*)d_in[11];
    const float* b2    = (const float*)d_in[12];
    const float* init  = (const float*)d_in[13];
    float* out = (float*)d_out;

    float* hbuf   = (float*)d_ws;                 // B*S*H fp32 = 134 MB
    float* incbuf = hbuf + (size_t)B * S * H;     // B*S fp32  = 1 MB

    hipLaunchKernelGGL(gru_layer0, dim3(B), dim3(512), 0, stream,
                       x, w_ih0, w_hh0, b_ih0, b_hh0, hbuf);
    hipLaunchKernelGGL(gru_layer1, dim3(B), dim3(512), 0, stream,
                       w_ih1, w_hh1, b_ih1, b_hh1, hbuf);
    hipLaunchKernelGGL(head_kernel, dim3((B * S) / 128), dim3(64), 0, stream,
                       hbuf, x, w1, b1, w2, b2, incbuf, 128);
    hipLaunchKernelGGL(cumsum_kernel, dim3(B), dim3(256), 0, stream,
                       incbuf, init, out);
}

// Round 4
// 7269.463 us; speedup vs baseline: 1.0536x; 1.0536x over previous
//
#include <hip/hip_runtime.h>
#include <cmath>

#define B 64
#define S 4096
#define NI 16
#define H 128
#define F 144   // H + NI

typedef float  v2f __attribute__((ext_vector_type(2)));
typedef _Float16 h2 __attribute__((ext_vector_type(2)));

__device__ __forceinline__ float sigf(float x) {
    return 1.0f / (1.0f + __expf(-x));
}
__device__ __forceinline__ float tanh_fast(float x) {
    x = fminf(fmaxf(x, -15.0f), 15.0f);
    const float e = __expf(2.0f * x);
    return (e - 1.0f) / (e + 1.0f);
}
// 2-stage quad butterfly via DPP quad_perm: every lane of the quad gets the sum.
__device__ __forceinline__ float quad_reduce(float v) {
    int t1 = __builtin_amdgcn_mov_dpp(__float_as_int(v), 0xB1, 0xf, 0xf, true); // xor 1
    v += __int_as_float(t1);
    int t2 = __builtin_amdgcn_mov_dpp(__float_as_int(v), 0x4E, 0xf, 0xf, true); // xor 2
    v += __int_as_float(t2);
    return v;
}
__device__ __forceinline__ h2 cvt2(float a, float b) {
    h2 r; r[0] = (_Float16)a; r[1] = (_Float16)b; return r;
}
// load 32 consecutive fp32 weights -> 16 packed half2 registers
__device__ __forceinline__ void load_row_h2(const float* p, h2* w) {
#pragma unroll
    for (int i = 0; i < 8; i++) {
        const float4 f = ((const float4*)p)[i];
        w[2 * i]     = cvt2(f.x, f.y);
        w[2 * i + 1] = cvt2(f.z, f.w);
    }
}

// ---------------------------------------------------------------------------
// Layer 0 GRU: 64 blocks x 512 threads. Quad owns output j = tid>>2; lane m
// owns k-quarter [32m,32m+32) (fp16-packed, 16 half2 per gate row) and
// x-quarter [4m,4m+4) (fp32). One barrier/step; activation redundant in-quad
// after DPP butterfly. LDS h state double-buffered fp16 (reads staggered
// (i+m)&3 -> conflict-free). Weight footprint ~60 VGPR -> register-resident.
// ---------------------------------------------------------------------------
__global__ __launch_bounds__(512, 2)
void gru_layer0(const float* __restrict__ x,
                const float* __restrict__ w_ih, const float* __restrict__ w_hh,
                const float* __restrict__ b_ih, const float* __restrict__ b_hh,
                float* __restrict__ h_out)
{
    __shared__ __align__(16) _Float16 sH[2][H];

    const int b   = blockIdx.x;
    const int tid = threadIdx.x;
    const int j   = tid >> 2;
    const int m   = tid & 3;

    h2 whr[16], whz[16], whn[16];
    load_row_h2(w_hh + (size_t)j * H + 32 * m,           whr);
    load_row_h2(w_hh + (size_t)(H + j) * H + 32 * m,     whz);
    load_row_h2(w_hh + (size_t)(2 * H + j) * H + 32 * m, whn);

    float4 wxr = *(const float4*)(w_ih + (size_t)j * NI + 4 * m);
    float4 wxz = *(const float4*)(w_ih + (size_t)(H + j) * NI + 4 * m);
    float4 wxn = *(const float4*)(w_ih + (size_t)(2 * H + j) * NI + 4 * m);

    const float b_r  = b_ih[j]         + b_hh[j];
    const float b_z  = b_ih[H + j]     + b_hh[H + j];
    const float b_in = b_ih[2 * H + j];
    const float b_hn = b_hh[2 * H + j];

    const float* xb  = x + (size_t)b * S * NI + 4 * m;
    float*       hob = h_out + (size_t)b * S * H;

    float4 xc  = *(const float4*)xb;          // x[0] quarter
    float4 xnx = *(const float4*)(xb + NI);   // x[1] quarter
    float hprev = 0.0f;
    if (tid < H) sH[0][tid] = (_Float16)0.0f;
    __syncthreads();

    for (int t = 0; t < S; t++) {
        const int cur = t & 1;
        const float4* hv = (const float4*)(&sH[cur][0]);   // 16B = 8 halves

        float ar = 0.f, az = 0.f, ahn = 0.f;
#pragma unroll
        for (int i = 0; i < 4; i++) {
            const int f = (i + m) & 3;                     // bank stagger
            const float4 q = hv[4 * m + f];
            const h2 p0 = __builtin_bit_cast(h2, q.x);
            const h2 p1 = __builtin_bit_cast(h2, q.y);
            const h2 p2 = __builtin_bit_cast(h2, q.z);
            const h2 p3 = __builtin_bit_cast(h2, q.w);
            ar  = __builtin_amdgcn_fdot2(p0, whr[4 * f + 0], ar,  false);
            ar  = __builtin_amdgcn_fdot2(p1, whr[4 * f + 1], ar,  false);
            ar  = __builtin_amdgcn_fdot2(p2, whr[4 * f + 2], ar,  false);
            ar  = __builtin_amdgcn_fdot2(p3, whr[4 * f + 3], ar,  false);
            az  = __builtin_amdgcn_fdot2(p0, whz[4 * f + 0], az,  false);
            az  = __builtin_amdgcn_fdot2(p1, whz[4 * f + 1], az,  false);
            az  = __builtin_amdgcn_fdot2(p2, whz[4 * f + 2], az,  false);
            az  = __builtin_amdgcn_fdot2(p3, whz[4 * f + 3], az,  false);
            ahn = __builtin_amdgcn_fdot2(p0, whn[4 * f + 0], ahn, false);
            ahn = __builtin_amdgcn_fdot2(p1, whn[4 * f + 1], ahn, false);
            ahn = __builtin_amdgcn_fdot2(p2, whn[4 * f + 2], ahn, false);
            ahn = __builtin_amdgcn_fdot2(p3, whn[4 * f + 3], ahn, false);
        }
        float ain = 0.f;
        ar  = fmaf(xc.x, wxr.x, ar);  ar  = fmaf(xc.y, wxr.y, ar);
        ar  = fmaf(xc.z, wxr.z, ar);  ar  = fmaf(xc.w, wxr.w, ar);
        az  = fmaf(xc.x, wxz.x, az);  az  = fmaf(xc.y, wxz.y, az);
        az  = fmaf(xc.z, wxz.z, az);  az  = fmaf(xc.w, wxz.w, az);
        ain = fmaf(xc.x, wxn.x, ain); ain = fmaf(xc.y, wxn.y, ain);
        ain = fmaf(xc.z, wxn.z, ain); ain = fmaf(xc.w, wxn.w, ain);

        const float vr  = quad_reduce(ar)  + b_r;
        const float vz  = quad_reduce(az)  + b_z;
        const float vhn = quad_reduce(ahn) + b_hn;
        const float vin = quad_reduce(ain) + b_in;

        xc = xnx;                                   // advance x pipeline
        if (t + 2 < S) xnx = *(const float4*)(xb + (size_t)(t + 2) * NI);

        const float r  = sigf(vr);
        const float z  = sigf(vz);
        const float n  = tanh_fast(vin + r * vhn);
        const float hn = n + z * (hprev - n);
        hprev = hn;
        if (m == 0) {
            sH[cur ^ 1][j] = (_Float16)hn;
            hob[(size_t)t * H + j] = hn;
        }
        __syncthreads();
    }
}

// ---------------------------------------------------------------------------
// Layer 1 GRU: 64 blocks x 512 threads, same quad layout. Per lane: quarters
// of 6 gate rows as 96 packed half2 VGPRs (~125 total pressure -> fits the
// compiler's 128-VGPR target, so no load sinking). h0 stream prefetched 3
// steps ahead (fp32 regs) and staged into fp16 LDS; h1 state double-buffered
// fp16; h1 overwrites h0 in place (h0[t+3] read before h1[t] write reaches it).
// ---------------------------------------------------------------------------
__global__ __launch_bounds__(512, 2)
void gru_layer1(const float* __restrict__ w_ih, const float* __restrict__ w_hh,
                const float* __restrict__ b_ih, const float* __restrict__ b_hh,
                float* __restrict__ hbuf)
{
    __shared__ __align__(16) _Float16 sHin[2][H];
    __shared__ __align__(16) _Float16 sH1[2][H];

    const int b   = blockIdx.x;
    const int tid = threadIdx.x;
    const int j   = tid >> 2;
    const int m   = tid & 3;

    h2 wir[16], wiz[16], win[16], whr[16], whz[16], whn[16];
    load_row_h2(w_ih + (size_t)j * H + 32 * m,           wir);
    load_row_h2(w_ih + (size_t)(H + j) * H + 32 * m,     wiz);
    load_row_h2(w_ih + (size_t)(2 * H + j) * H + 32 * m, win);
    load_row_h2(w_hh + (size_t)j * H + 32 * m,           whr);
    load_row_h2(w_hh + (size_t)(H + j) * H + 32 * m,     whz);
    load_row_h2(w_hh + (size_t)(2 * H + j) * H + 32 * m, whn);

    const float b_r  = b_ih[j]         + b_hh[j];
    const float b_z  = b_ih[H + j]     + b_hh[H + j];
    const float b_in = b_ih[2 * H + j];
    const float b_hn = b_hh[2 * H + j];

    float* hb = hbuf + (size_t)b * S * H;

    float pre1 = 0.f, pre2 = 0.f;
    if (tid < H) {
        sHin[0][tid] = (_Float16)hb[tid];   // h0[0]
        sH1[0][tid]  = (_Float16)0.0f;      // h1[-1]
        pre1 = hb[H + tid];                 // h0[1]
        pre2 = hb[2 * H + tid];             // h0[2]
    }
    float hprev = 0.0f;
    __syncthreads();

    for (int t = 0; t < S; t++) {
        const int cur = t & 1;
        const float4* g0 = (const float4*)(&sHin[cur][0]);
        const float4* g1 = (const float4*)(&sH1[cur][0]);

        float ar = 0.f, az = 0.f, ain = 0.f, ahn = 0.f;
#pragma unroll
        for (int i = 0; i < 4; i++) {
            const int f = (i + m) & 3;                     // bank stagger
            const float4 qa = g0[4 * m + f];
            const float4 qc = g1[4 * m + f];
            const h2 a0 = __builtin_bit_cast(h2, qa.x);
            const h2 a1 = __builtin_bit_cast(h2, qa.y);
            const h2 a2 = __builtin_bit_cast(h2, qa.z);
            const h2 a3 = __builtin_bit_cast(h2, qa.w);
            const h2 c0 = __builtin_bit_cast(h2, qc.x);
            const h2 c1 = __builtin_bit_cast(h2, qc.y);
            const h2 c2 = __builtin_bit_cast(h2, qc.z);
            const h2 c3 = __builtin_bit_cast(h2, qc.w);
            ar  = __builtin_amdgcn_fdot2(a0, wir[4 * f + 0], ar,  false);
            ar  = __builtin_amdgcn_fdot2(a1, wir[4 * f + 1], ar,  false);
            ar  = __builtin_amdgcn_fdot2(a2, wir[4 * f + 2], ar,  false);
            ar  = __builtin_amdgcn_fdot2(a3, wir[4 * f + 3], ar,  false);
            ar  = __builtin_amdgcn_fdot2(c0, whr[4 * f + 0], ar,  false);
            ar  = __builtin_amdgcn_fdot2(c1, whr[4 * f + 1], ar,  false);
            ar  = __builtin_amdgcn_fdot2(c2, whr[4 * f + 2], ar,  false);
            ar  = __builtin_amdgcn_fdot2(c3, whr[4 * f + 3], ar,  false);
            az  = __builtin_amdgcn_fdot2(a0, wiz[4 * f + 0], az,  false);
            az  = __builtin_amdgcn_fdot2(a1, wiz[4 * f + 1], az,  false);
            az  = __builtin_amdgcn_fdot2(a2, wiz[4 * f + 2], az,  false);
            az  = __builtin_amdgcn_fdot2(a3, wiz[4 * f + 3], az,  false);
            az  = __builtin_amdgcn_fdot2(c0, whz[4 * f + 0], az,  false);
            az  = __builtin_amdgcn_fdot2(c1, whz[4 * f + 1], az,  false);
            az  = __builtin_amdgcn_fdot2(c2, whz[4 * f + 2], az,  false);
            az  = __builtin_amdgcn_fdot2(c3, whz[4 * f + 3], az,  false);
            ain = __builtin_amdgcn_fdot2(a0, win[4 * f + 0], ain, false);
            ain = __builtin_amdgcn_fdot2(a1, win[4 * f + 1], ain, false);
            ain = __builtin_amdgcn_fdot2(a2, win[4 * f + 2], ain, false);
            ain = __builtin_amdgcn_fdot2(a3, win[4 * f + 3], ain, false);
            ahn = __builtin_amdgcn_fdot2(c0, whn[4 * f + 0], ahn, false);
            ahn = __builtin_amdgcn_fdot2(c1, whn[4 * f + 1], ahn, false);
            ahn = __builtin_amdgcn_fdot2(c2, whn[4 * f + 2], ahn, false);
            ahn = __builtin_amdgcn_fdot2(c3, whn[4 * f + 3], ahn, false);
        }
        const float vr  = quad_reduce(ar)  + b_r;
        const float vz  = quad_reduce(az)  + b_z;
        const float vin = quad_reduce(ain) + b_in;
        const float vhn = quad_reduce(ahn) + b_hn;

        // stage h0[t+1] into the other buffer; refill pipeline with h0[t+3]
        if (tid < H) {
            sHin[cur ^ 1][tid] = (_Float16)pre1;
            pre1 = pre2;
            if (t + 3 < S) pre2 = hb[(size_t)(t + 3) * H + tid];
        }

        const float r  = sigf(vr);
        const float z  = sigf(vz);
        const float n  = tanh_fast(vin + r * vhn);
        const float hn = n + z * (hprev - n);
        hprev = hn;
        if (m == 0) {
            sH1[cur ^ 1][j] = (_Float16)hn;
            hb[(size_t)t * H + j] = hn;     // overwrite h0[t] with h1[t]
        }
        __syncthreads();
    }
}

// ---------------------------------------------------------------------------
// MLP head, batched over all B*S rows. One wave per block; lane owns hidden
// unit; w1 row register-resident (fp32).
// ---------------------------------------------------------------------------
__global__ __launch_bounds__(64, 2)
void head_kernel(const float* __restrict__ h1, const float* __restrict__ x,
                 const float* __restrict__ w1, const float* __restrict__ b1,
                 const float* __restrict__ w2, const float* __restrict__ b2,
                 float* __restrict__ inc, int rows_per_blk)
{
    __shared__ float sC[2][F];
    const int lane = threadIdx.x;

    float wr[F];
#pragma unroll
    for (int f = 0; f < F; f++) wr[f] = w1[lane * F + f];
    const float b1v = b1[lane];
    const float w2v = w2[lane];
    const float b2v = b2[0];

    const int row0 = blockIdx.x * rows_per_blk;

    {
        const int r = row0;
        sC[0][lane]      = h1[(size_t)r * H + lane];
        sC[0][64 + lane] = h1[(size_t)r * H + 64 + lane];
        if (lane < NI) sC[0][H + lane] = x[(size_t)r * NI + lane];
    }
    __syncthreads();

    for (int i = 0; i < rows_per_blk; i++) {
        const int row = row0 + i;
        const int cur = i & 1;
        const int nxt = cur ^ 1;

        float p0 = 0.f, p1 = 0.f, p2 = 0.f;
        if (i + 1 < rows_per_blk) {
            const int rn = row + 1;
            p0 = h1[(size_t)rn * H + lane];
            p1 = h1[(size_t)rn * H + 64 + lane];
            if (lane < NI) p2 = x[(size_t)rn * NI + lane];
        }

        float acc = b1v;
#pragma unroll
        for (int f = 0; f < F; f++) acc += sC[cur][f] * wr[f];

        if (i + 1 < rows_per_blk) {
            sC[nxt][lane]      = p0;
            sC[nxt][64 + lane] = p1;
            if (lane < NI) sC[nxt][H + lane] = p2;
        }

        float v = fmaxf(acc, 0.0f) * w2v;
#pragma unroll
        for (int off = 32; off > 0; off >>= 1) v += __shfl_xor(v, off, 64);

        if (lane == 0) inc[row] = tanh_fast(v + b2v) * 0.125f;
        __syncthreads();
    }
}

// ---------------------------------------------------------------------------
// Inclusive cumsum over S per batch + initial offset. One block per batch.
// ---------------------------------------------------------------------------
__global__ __launch_bounds__(256)
void cumsum_kernel(const float* __restrict__ inc, const float* __restrict__ init,
                   float* __restrict__ out)
{
    __shared__ float sW[4];
    const int b = blockIdx.x;
    const int tid = threadIdx.x;
    const int lane = tid & 63;
    const int wid = tid >> 6;

    const float* ib = inc + (size_t)b * S;
    float v[16];
#pragma unroll
    for (int i = 0; i < 16; i++) v[i] = ib[tid * 16 + i];

    float run = 0.f;
#pragma unroll
    for (int i = 0; i < 16; i++) { run += v[i]; v[i] = run; }

    float t = run;
#pragma unroll
    for (int off = 1; off < 64; off <<= 1) {
        float u = __shfl_up(t, off, 64);
        if (lane >= off) t += u;
    }
    const float excl = t - run;
    if (lane == 63) sW[wid] = t;
    __syncthreads();

    float wo = 0.f;
#pragma unroll
    for (int w = 0; w < 4; w++) if (w < wid) wo += sW[w];

    const float prefix = wo + excl + init[0];
    float* ob = out + (size_t)b * S;
#pragma unroll
    for (int i = 0; i < 16; i++) ob[tid * 16 + i] = prefix + v[i];
}

// ---------------------------------------------------------------------------
extern "C" void kernel_launch(void* const* d_in, const int* in_sizes, int n_in,
                              void* d_out, int out_size, void* d_ws, size_t ws_size,
                              hipStream_t stream)
{
    const float* x     = (const float*)d_in[0];
    const float* w_ih0 = (const float*)d_in[1];
    const float* w_hh0 = (const float*)d_in[2];
    const float* b_ih0 = (const float*)d_in[3];
    const float* b_hh0 = (const float*)d_in[4];
    const float* w_ih1 = (const float*)d_in[5];
    const float* w_hh1 = (const float*)d_in[6];
    const float* b_ih1 = (const float*)d_in[7];
    const float* b_hh1 = (const float*)d_in[8];
    const float* w1    = (const float*)d_in[9];
    const float* b1    = (const float*)d_in[10];
    const float* w2    = (const float*)d_in[11];
    const float* b2    = (const float*)d_in[12];
    const float* init  = (const float*)d_in[13];
    float* out = (float*)d_out;

    float* hbuf   = (float*)d_ws;                 // B*S*H fp32 = 134 MB
    float* incbuf = hbuf + (size_t)B * S * H;     // B*S fp32  = 1 MB

    hipLaunchKernelGGL(gru_layer0, dim3(B), dim3(512), 0, stream,
                       x, w_ih0, w_hh0, b_ih0, b_hh0, hbuf);
    hipLaunchKernelGGL(gru_layer1, dim3(B), dim3(512), 0, stream,
                       w_ih1, w_hh1, b_ih1, b_hh1, hbuf);
    hipLaunchKernelGGL(head_kernel, dim3((B * S) / 128), dim3(64), 0, stream,
                       hbuf, x, w1, b1, w2, b2, incbuf, 128);
    hipLaunchKernelGGL(cumsum_kernel, dim3(B), dim3(256), 0, stream,
                       incbuf, init, out);
}

// Round 5
// 6543.271 us; speedup vs baseline: 1.1705x; 1.1110x over previous
//
#include <hip/hip_runtime.h>
#include <cmath>

#define B 64
#define S 4096
#define NI 16
#define H 128
#define F 144   // H + NI
#define CH 16   // timesteps per staging chunk

typedef _Float16 h2 __attribute__((ext_vector_type(2)));

__device__ __forceinline__ float rcp_fast(float x) { return __builtin_amdgcn_rcpf(x); }
__device__ __forceinline__ float sigf(float x) {
    return rcp_fast(1.0f + __expf(-x));
}
__device__ __forceinline__ float tanh_fast(float x) {
    x = fminf(fmaxf(x, -15.0f), 15.0f);
    const float e = __expf(2.0f * x);
    return (e - 1.0f) * rcp_fast(e + 1.0f);
}
// quad butterfly (lanes 0-3 of each quad end with the 4-lane sum)
__device__ __forceinline__ float quad_reduce(float v) {
    int t1 = __builtin_amdgcn_mov_dpp(__float_as_int(v), 0xB1, 0xf, 0xf, true); // xor 1
    v += __int_as_float(t1);
    int t2 = __builtin_amdgcn_mov_dpp(__float_as_int(v), 0x4E, 0xf, 0xf, true); // xor 2
    v += __int_as_float(t2);
    return v;
}
// 8-lane sum: quad butterfly + xor-4 swizzle (BitMode 0x101F)
__device__ __forceinline__ float oct_reduce(float v) {
    v = quad_reduce(v);
    v += __int_as_float(__builtin_amdgcn_ds_swizzle(__float_as_int(v), 0x101F));
    return v;
}
__device__ __forceinline__ h2 cvt2(float a, float b) {
    h2 r; r[0] = (_Float16)a; r[1] = (_Float16)b; return r;
}
// convert 8 consecutive fp32 -> 4 packed half2 regs
__device__ __forceinline__ void cvt8(const float* p, h2* w) {
    const float4 f0 = ((const float4*)p)[0];
    const float4 f1 = ((const float4*)p)[1];
    w[0] = cvt2(f0.x, f0.y); w[1] = cvt2(f0.z, f0.w);
    w[2] = cvt2(f1.x, f1.y); w[3] = cvt2(f1.z, f1.w);
}

// ---------------------------------------------------------------------------
// Layer 0: 64 blocks x 512 threads. Quad owns output j=tid>>2; lane m owns
// k-quarter [32m,32m+32) (fp16) + x-quarter [4m,4m+4) (fp32). Weights are
// LOAD-permuted so read slot i uses compile-time register indices while the
// LDS address carries the (i+m)&3 bank stagger. NO per-step global ops:
// x staged per-16-step chunk into LDS; h output accumulated in LDS and
// flushed every 16 steps (one vmcnt drain per 16 barriers).
// ---------------------------------------------------------------------------
__global__ __launch_bounds__(512, 2)
void gru_layer0(const float* __restrict__ x,
                const float* __restrict__ w_ih, const float* __restrict__ w_hh,
                const float* __restrict__ b_ih, const float* __restrict__ b_hh,
                float* __restrict__ h_out)
{
    __shared__ __align__(16) _Float16 sH[2][H];        // state (step ping-pong)
    __shared__ __align__(16) float    sX[2][CH][NI];   // x chunks (2 KB)
    __shared__ __align__(16) float    sHo[2][CH][H];   // h-out accum (16 KB)

    const int b   = blockIdx.x;
    const int tid = threadIdx.x;
    const int j   = tid >> 2;
    const int m   = tid & 3;

    // weights, load-permuted: slot i holds global sub-chunk f=(i+m)&3
    h2 whr[16], whz[16], whn[16];
#pragma unroll
    for (int i = 0; i < 4; i++) {
        const int f = (i + m) & 3;
        cvt8(w_hh + (size_t)j * H         + 32 * m + 8 * f, &whr[4 * i]);
        cvt8(w_hh + (size_t)(H + j) * H   + 32 * m + 8 * f, &whz[4 * i]);
        cvt8(w_hh + (size_t)(2*H + j) * H + 32 * m + 8 * f, &whn[4 * i]);
    }
    const float4 wxr = *(const float4*)(w_ih + (size_t)j * NI + 4 * m);
    const float4 wxz = *(const float4*)(w_ih + (size_t)(H + j) * NI + 4 * m);
    const float4 wxn = *(const float4*)(w_ih + (size_t)(2*H + j) * NI + 4 * m);

    const float b_r  = b_ih[j]       + b_hh[j];
    const float b_z  = b_ih[H + j]   + b_hh[H + j];
    const float b_in = b_ih[2*H + j];
    const float b_hn = b_hh[2*H + j];

    const float* xb  = x + (size_t)b * S * NI;
    float*       hob = h_out + (size_t)b * S * H;

    // prologue: stage x chunk 0 (256 floats)
    if (tid < 64) {
        ((float4*)&sX[0][0][0])[tid] = ((const float4*)xb)[tid];
    }
    float hprev = 0.0f;
    if (tid < H) sH[0][tid] = (_Float16)0.0f;
    __syncthreads();

    for (int t = 0; t < S; t++) {
        const int cur = t & 1;
        const int tw  = t & (CH - 1);
        const int c   = t >> 4;

        if (tw == 0) {
            if (c > 0) {   // flush h chunk c-1 (2048 floats, 512 lanes x float4)
                const float4 v = ((const float4*)&sHo[(c - 1) & 1][0][0])[tid];
                ((float4*)(hob + (size_t)(c - 1) * CH * H))[tid] = v;
            }
            if (c + 1 < S / CH && tid < 64) {   // stage x chunk c+1
                ((float4*)&sX[(c + 1) & 1][0][0])[tid] =
                    ((const float4*)(xb + (size_t)(c + 1) * CH * NI))[tid];
            }
        }

        const float4* hv = (const float4*)&sH[cur][0];   // 16B = 8 halves
        float ar = 0.f, az = 0.f, ahn = 0.f;
#pragma unroll
        for (int i = 0; i < 4; i++) {
            const int f = (i + m) & 3;                   // bank stagger (address only)
            const float4 q = hv[4 * m + f];
            const h2 p0 = __builtin_bit_cast(h2, q.x);
            const h2 p1 = __builtin_bit_cast(h2, q.y);
            const h2 p2 = __builtin_bit_cast(h2, q.z);
            const h2 p3 = __builtin_bit_cast(h2, q.w);
            ar  = __builtin_amdgcn_fdot2(p0, whr[4*i+0], ar,  false);
            ar  = __builtin_amdgcn_fdot2(p1, whr[4*i+1], ar,  false);
            ar  = __builtin_amdgcn_fdot2(p2, whr[4*i+2], ar,  false);
            ar  = __builtin_amdgcn_fdot2(p3, whr[4*i+3], ar,  false);
            az  = __builtin_amdgcn_fdot2(p0, whz[4*i+0], az,  false);
            az  = __builtin_amdgcn_fdot2(p1, whz[4*i+1], az,  false);
            az  = __builtin_amdgcn_fdot2(p2, whz[4*i+2], az,  false);
            az  = __builtin_amdgcn_fdot2(p3, whz[4*i+3], az,  false);
            ahn = __builtin_amdgcn_fdot2(p0, whn[4*i+0], ahn, false);
            ahn = __builtin_amdgcn_fdot2(p1, whn[4*i+1], ahn, false);
            ahn = __builtin_amdgcn_fdot2(p2, whn[4*i+2], ahn, false);
            ahn = __builtin_amdgcn_fdot2(p3, whn[4*i+3], ahn, false);
        }
        const float4 xq = *(const float4*)&sX[c & 1][tw][4 * m];
        float ain = 0.f;
        ar  = fmaf(xq.x, wxr.x, ar);  ar  = fmaf(xq.y, wxr.y, ar);
        ar  = fmaf(xq.z, wxr.z, ar);  ar  = fmaf(xq.w, wxr.w, ar);
        az  = fmaf(xq.x, wxz.x, az);  az  = fmaf(xq.y, wxz.y, az);
        az  = fmaf(xq.z, wxz.z, az);  az  = fmaf(xq.w, wxz.w, az);
        ain = fmaf(xq.x, wxn.x, ain); ain = fmaf(xq.y, wxn.y, ain);
        ain = fmaf(xq.z, wxn.z, ain); ain = fmaf(xq.w, wxn.w, ain);

        const float vr  = quad_reduce(ar)  + b_r;
        const float vz  = quad_reduce(az)  + b_z;
        const float vhn = quad_reduce(ahn) + b_hn;
        const float vin = quad_reduce(ain) + b_in;

        const float r  = sigf(vr);
        const float z  = sigf(vz);
        const float n  = tanh_fast(vin + r * vhn);
        const float hn = n + z * (hprev - n);
        hprev = hn;
        if (m == 0) {
            sH[cur ^ 1][j]   = (_Float16)hn;
            sHo[c & 1][tw][j] = hn;
        }
        __syncthreads();
    }
    {   // epilogue: flush last chunk
        const int c = S / CH - 1;
        const float4 v = ((const float4*)&sHo[c & 1][0][0])[tid];
        ((float4*)(hob + (size_t)c * CH * H))[tid] = v;
    }
}

// ---------------------------------------------------------------------------
// Layer 1: 64 blocks x 1024 threads. Octet owns output j=tid>>3; lane m owns
// k-chunk [16m,16m+16) of all 6 gate rows (48 packed half2 VGPRs -> ~80 total
// pressure, far under the 128 tier). h0 staged per-chunk fp32->fp16 into LDS;
// h1 output accumulated in LDS, flushed every 16 steps, overwriting the h0
// buffer in place (h0 chunk k is read 2 chunks before h1 chunk k is written).
// Reduction: quad DPP butterfly + one ds_swizzle xor-4.
// ---------------------------------------------------------------------------
__global__ __launch_bounds__(1024, 4)
void gru_layer1(const float* __restrict__ w_ih, const float* __restrict__ w_hh,
                const float* __restrict__ b_ih, const float* __restrict__ b_hh,
                float* __restrict__ hbuf)
{
    __shared__ __align__(16) _Float16 sIn[2][CH][H];   // h0 chunks fp16 (8 KB)
    __shared__ __align__(16) _Float16 sH1[2][H];       // h1 state
    __shared__ __align__(16) float    sHo[2][CH][H];   // h1-out accum (16 KB)

    const int b   = blockIdx.x;
    const int tid = threadIdx.x;
    const int j   = tid >> 3;
    const int m   = tid & 7;

    // weights, load-permuted: slot i holds global sub-chunk f=(i+m)&1
    h2 wir[8], wiz[8], win[8], whr[8], whz[8], whn[8];
#pragma unroll
    for (int i = 0; i < 2; i++) {
        const int f = (i + m) & 1;
        const int o = 16 * m + 8 * f;
        cvt8(w_ih + (size_t)j * H         + o, &wir[4 * i]);
        cvt8(w_ih + (size_t)(H + j) * H   + o, &wiz[4 * i]);
        cvt8(w_ih + (size_t)(2*H + j) * H + o, &win[4 * i]);
        cvt8(w_hh + (size_t)j * H         + o, &whr[4 * i]);
        cvt8(w_hh + (size_t)(H + j) * H   + o, &whz[4 * i]);
        cvt8(w_hh + (size_t)(2*H + j) * H + o, &whn[4 * i]);
    }
    const float b_r  = b_ih[j]       + b_hh[j];
    const float b_z  = b_ih[H + j]   + b_hh[H + j];
    const float b_in = b_ih[2*H + j];
    const float b_hn = b_hh[2*H + j];

    float* hb = hbuf + (size_t)b * S * H;

    {   // prologue: stage h0 chunk 0 (2048 floats, 1024 lanes x float2)
        const float2 v = ((const float2*)hb)[tid];
        ((h2*)&sIn[0][0][0])[tid] = cvt2(v.x, v.y);
    }
    float hprev = 0.0f;
    if (tid < H) sH1[0][tid] = (_Float16)0.0f;
    __syncthreads();

    for (int t = 0; t < S; t++) {
        const int cur = t & 1;
        const int tw  = t & (CH - 1);
        const int c   = t >> 4;

        if (tw == 0) {
            if (c > 0) {   // flush h1 chunk c-1
                const float2 v = ((const float2*)&sHo[(c - 1) & 1][0][0])[tid];
                ((float2*)(hb + (size_t)(c - 1) * CH * H))[tid] = v;
            }
            if (c + 1 < S / CH) {   // stage h0 chunk c+1 (fp32 -> fp16)
                const float2 v = ((const float2*)(hb + (size_t)(c + 1) * CH * H))[tid];
                ((h2*)&sIn[(c + 1) & 1][0][0])[tid] = cvt2(v.x, v.y);
            }
        }

        const float4* qa = (const float4*)&sIn[c & 1][tw][16 * m];  // 2 x 16B
        const float4* qc = (const float4*)&sH1[cur][16 * m];
        float ar = 0.f, az = 0.f, ain = 0.f, ahn = 0.f;
#pragma unroll
        for (int i = 0; i < 2; i++) {
            const int f = (i + m) & 1;                  // address-side stagger
            const float4 A = qa[f];
            const float4 C = qc[f];
            const h2 a0 = __builtin_bit_cast(h2, A.x);
            const h2 a1 = __builtin_bit_cast(h2, A.y);
            const h2 a2 = __builtin_bit_cast(h2, A.z);
            const h2 a3 = __builtin_bit_cast(h2, A.w);
            const h2 c0 = __builtin_bit_cast(h2, C.x);
            const h2 c1 = __builtin_bit_cast(h2, C.y);
            const h2 c2 = __builtin_bit_cast(h2, C.z);
            const h2 c3 = __builtin_bit_cast(h2, C.w);
            ar  = __builtin_amdgcn_fdot2(a0, wir[4*i+0], ar,  false);
            ar  = __builtin_amdgcn_fdot2(a1, wir[4*i+1], ar,  false);
            ar  = __builtin_amdgcn_fdot2(a2, wir[4*i+2], ar,  false);
            ar  = __builtin_amdgcn_fdot2(a3, wir[4*i+3], ar,  false);
            ar  = __builtin_amdgcn_fdot2(c0, whr[4*i+0], ar,  false);
            ar  = __builtin_amdgcn_fdot2(c1, whr[4*i+1], ar,  false);
            ar  = __builtin_amdgcn_fdot2(c2, whr[4*i+2], ar,  false);
            ar  = __builtin_amdgcn_fdot2(c3, whr[4*i+3], ar,  false);
            az  = __builtin_amdgcn_fdot2(a0, wiz[4*i+0], az,  false);
            az  = __builtin_amdgcn_fdot2(a1, wiz[4*i+1], az,  false);
            az  = __builtin_amdgcn_fdot2(a2, wiz[4*i+2], az,  false);
            az  = __builtin_amdgcn_fdot2(a3, wiz[4*i+3], az,  false);
            az  = __builtin_amdgcn_fdot2(c0, whz[4*i+0], az,  false);
            az  = __builtin_amdgcn_fdot2(c1, whz[4*i+1], az,  false);
            az  = __builtin_amdgcn_fdot2(c2, whz[4*i+2], az,  false);
            az  = __builtin_amdgcn_fdot2(c3, whz[4*i+3], az,  false);
            ain = __builtin_amdgcn_fdot2(a0, win[4*i+0], ain, false);
            ain = __builtin_amdgcn_fdot2(a1, win[4*i+1], ain, false);
            ain = __builtin_amdgcn_fdot2(a2, win[4*i+2], ain, false);
            ain = __builtin_amdgcn_fdot2(a3, win[4*i+3], ain, false);
            ahn = __builtin_amdgcn_fdot2(c0, whn[4*i+0], ahn, false);
            ahn = __builtin_amdgcn_fdot2(c1, whn[4*i+1], ahn, false);
            ahn = __builtin_amdgcn_fdot2(c2, whn[4*i+2], ahn, false);
            ahn = __builtin_amdgcn_fdot2(c3, whn[4*i+3], ahn, false);
        }
        const float vr  = oct_reduce(ar)  + b_r;
        const float vz  = oct_reduce(az)  + b_z;
        const float vin = oct_reduce(ain) + b_in;
        const float vhn = oct_reduce(ahn) + b_hn;

        const float r  = sigf(vr);
        const float z  = sigf(vz);
        const float n  = tanh_fast(vin + r * vhn);
        const float hn = n + z * (hprev - n);
        hprev = hn;
        if (m == 0) {
            sH1[cur ^ 1][j]   = (_Float16)hn;
            sHo[c & 1][tw][j] = hn;
        }
        __syncthreads();
    }
    {   // epilogue: flush last chunk
        const int c = S / CH - 1;
        const float2 v = ((const float2*)&sHo[c & 1][0][0])[tid];
        ((float2*)(hb + (size_t)c * CH * H))[tid] = v;
    }
}

// ---------------------------------------------------------------------------
// MLP head, batched over all B*S rows. One wave per block.
// ---------------------------------------------------------------------------
__global__ __launch_bounds__(64, 2)
void head_kernel(const float* __restrict__ h1, const float* __restrict__ x,
                 const float* __restrict__ w1, const float* __restrict__ b1,
                 const float* __restrict__ w2, const float* __restrict__ b2,
                 float* __restrict__ inc, int rows_per_blk)
{
    __shared__ float sC[2][F];
    const int lane = threadIdx.x;

    float wr[F];
#pragma unroll
    for (int f = 0; f < F; f++) wr[f] = w1[lane * F + f];
    const float b1v = b1[lane];
    const float w2v = w2[lane];
    const float b2v = b2[0];

    const int row0 = blockIdx.x * rows_per_blk;
    {
        const int r = row0;
        sC[0][lane]      = h1[(size_t)r * H + lane];
        sC[0][64 + lane] = h1[(size_t)r * H + 64 + lane];
        if (lane < NI) sC[0][H + lane] = x[(size_t)r * NI + lane];
    }
    __syncthreads();

    for (int i = 0; i < rows_per_blk; i++) {
        const int row = row0 + i;
        const int cur = i & 1;
        const int nxt = cur ^ 1;

        float p0 = 0.f, p1 = 0.f, p2 = 0.f;
        if (i + 1 < rows_per_blk) {
            const int rn = row + 1;
            p0 = h1[(size_t)rn * H + lane];
            p1 = h1[(size_t)rn * H + 64 + lane];
            if (lane < NI) p2 = x[(size_t)rn * NI + lane];
        }

        float acc = b1v;
#pragma unroll
        for (int f = 0; f < F; f++) acc += sC[cur][f] * wr[f];

        if (i + 1 < rows_per_blk) {
            sC[nxt][lane]      = p0;
            sC[nxt][64 + lane] = p1;
            if (lane < NI) sC[nxt][H + lane] = p2;
        }

        float v = fmaxf(acc, 0.0f) * w2v;
#pragma unroll
        for (int off = 32; off > 0; off >>= 1) v += __shfl_xor(v, off, 64);

        if (lane == 0) inc[row] = tanh_fast(v + b2v) * 0.125f;
        __syncthreads();
    }
}

// ---------------------------------------------------------------------------
// Inclusive cumsum over S per batch + initial offset. One block per batch.
// ---------------------------------------------------------------------------
__global__ __launch_bounds__(256)
void cumsum_kernel(const float* __restrict__ inc, const float* __restrict__ init,
                   float* __restrict__ out)
{
    __shared__ float sW[4];
    const int b = blockIdx.x;
    const int tid = threadIdx.x;
    const int lane = tid & 63;
    const int wid = tid >> 6;

    const float* ib = inc + (size_t)b * S;
    float v[16];
#pragma unroll
    for (int i = 0; i < 16; i++) v[i] = ib[tid * 16 + i];

    float run = 0.f;
#pragma unroll
    for (int i = 0; i < 16; i++) { run += v[i]; v[i] = run; }

    float t = run;
#pragma unroll
    for (int off = 1; off < 64; off <<= 1) {
        float u = __shfl_up(t, off, 64);
        if (lane >= off) t += u;
    }
    const float excl = t - run;
    if (lane == 63) sW[wid] = t;
    __syncthreads();

    float wo = 0.f;
#pragma unroll
    for (int w = 0; w < 4; w++) if (w < wid) wo += sW[w];

    const float prefix = wo + excl + init[0];
    float* ob = out + (size_t)b * S;
#pragma unroll
    for (int i = 0; i < 16; i++) ob[tid * 16 + i] = prefix + v[i];
}

// ---------------------------------------------------------------------------
extern "C" void kernel_launch(void* const* d_in, const int* in_sizes, int n_in,
                              void* d_out, int out_size, void* d_ws, size_t ws_size,
                              hipStream_t stream)
{
    const float* x     = (const float*)d_in[0];
    const float* w_ih0 = (const float*)d_in[1];
    const float* w_hh0 = (const float*)d_in[2];
    const float* b_ih0 = (const float*)d_in[3];
    const float* b_hh0 = (const float*)d_in[4];
    const float* w_ih1 = (const float*)d_in[5];
    const float* w_hh1 = (const float*)d_in[6];
    const float* b_ih1 = (const float*)d_in[7];
    const float* b_hh1 = (const float*)d_in[8];
    const float* w1    = (const float*)d_in[9];
    const float* b1    = (const float*)d_in[10];
    const float* w2    = (const float*)d_in[11];
    const float* b2    = (const float*)d_in[12];
    const float* init  = (const float*)d_in[13];
    float* out = (float*)d_out;

    float* hbuf   = (float*)d_ws;                 // B*S*H fp32 = 134 MB
    float* incbuf = hbuf + (size_t)B * S * H;     // B*S fp32  = 1 MB

    hipLaunchKernelGGL(gru_layer0, dim3(B), dim3(512), 0, stream,
                       x, w_ih0, w_hh0, b_ih0, b_hh0, hbuf);
    hipLaunchKernelGGL(gru_layer1, dim3(B), dim3(1024), 0, stream,
                       w_ih1, w_hh1, b_ih1, b_hh1, hbuf);
    hipLaunchKernelGGL(head_kernel, dim3((B * S) / 128), dim3(64), 0, stream,
                       hbuf, x, w1, b1, w2, b2, incbuf, 128);
    hipLaunchKernelGGL(cumsum_kernel, dim3(B), dim3(256), 0, stream,
                       incbuf, init, out);
}

// Round 6
// 5819.268 us; speedup vs baseline: 1.3161x; 1.1244x over previous
//
#include <hip/hip_runtime.h>
#include <cmath>

#define B 64
#define S 4096
#define NI 16
#define H 128
#define F 144   // H + NI
#define CH 16   // timesteps per staging chunk

typedef _Float16 h2 __attribute__((ext_vector_type(2)));
typedef _Float16 h4v __attribute__((ext_vector_type(4)));

__device__ __forceinline__ float rcp_fast(float x) { return __builtin_amdgcn_rcpf(x); }
__device__ __forceinline__ float sigf(float x) {
    return rcp_fast(1.0f + __expf(-x));
}
// tanh(x) = 2*sigmoid(2x) - 1 : mul, exp, add, rcp, fma (saturates correctly at +-inf)
__device__ __forceinline__ float tanh_fast(float x) {
    const float e = __expf(-2.0f * x);
    return fmaf(2.0f, rcp_fast(1.0f + e), -1.0f);
}
// quad butterfly (all 4 lanes of each quad end with the 4-lane sum)
__device__ __forceinline__ float quad_reduce(float v) {
    int t1 = __builtin_amdgcn_mov_dpp(__float_as_int(v), 0xB1, 0xf, 0xf, true); // xor 1
    v += __int_as_float(t1);
    int t2 = __builtin_amdgcn_mov_dpp(__float_as_int(v), 0x4E, 0xf, 0xf, true); // xor 2
    v += __int_as_float(t2);
    return v;
}
__device__ __forceinline__ h2 cvt2(float a, float b) {
    h2 r; r[0] = (_Float16)a; r[1] = (_Float16)b; return r;
}
// convert 8 consecutive fp32 -> 4 packed half2 regs
__device__ __forceinline__ void cvt8(const float* p, h2* w) {
    const float4 f0 = ((const float4*)p)[0];
    const float4 f1 = ((const float4*)p)[1];
    w[0] = cvt2(f0.x, f0.y); w[1] = cvt2(f0.z, f0.w);
    w[2] = cvt2(f1.x, f1.y); w[3] = cvt2(f1.z, f1.w);
}

// ---------------------------------------------------------------------------
// Layer 0: 64 blocks x 512 threads, quad owns j=tid>>2, lane m owns k-quarter
// [32m,32m+32) fp16 + x-quarter [4m,4m+4) fp32. Load-permuted weights
// (compile-time register indices, staggered LDS addresses). Chunked staging:
// no per-step global ops. (unchanged from round 5 except tanh_fast)
// ---------------------------------------------------------------------------
__global__ __launch_bounds__(512, 2)
void gru_layer0(const float* __restrict__ x,
                const float* __restrict__ w_ih, const float* __restrict__ w_hh,
                const float* __restrict__ b_ih, const float* __restrict__ b_hh,
                float* __restrict__ h_out)
{
    __shared__ __align__(16) _Float16 sH[2][H];
    __shared__ __align__(16) float    sX[2][CH][NI];
    __shared__ __align__(16) float    sHo[2][CH][H];

    const int b   = blockIdx.x;
    const int tid = threadIdx.x;
    const int j   = tid >> 2;
    const int m   = tid & 3;

    h2 whr[16], whz[16], whn[16];
#pragma unroll
    for (int i = 0; i < 4; i++) {
        const int f = (i + m) & 3;
        cvt8(w_hh + (size_t)j * H         + 32 * m + 8 * f, &whr[4 * i]);
        cvt8(w_hh + (size_t)(H + j) * H   + 32 * m + 8 * f, &whz[4 * i]);
        cvt8(w_hh + (size_t)(2*H + j) * H + 32 * m + 8 * f, &whn[4 * i]);
    }
    const float4 wxr = *(const float4*)(w_ih + (size_t)j * NI + 4 * m);
    const float4 wxz = *(const float4*)(w_ih + (size_t)(H + j) * NI + 4 * m);
    const float4 wxn = *(const float4*)(w_ih + (size_t)(2*H + j) * NI + 4 * m);

    const float b_r  = b_ih[j]       + b_hh[j];
    const float b_z  = b_ih[H + j]   + b_hh[H + j];
    const float b_in = b_ih[2*H + j];
    const float b_hn = b_hh[2*H + j];

    const float* xb  = x + (size_t)b * S * NI;
    float*       hob = h_out + (size_t)b * S * H;

    if (tid < 64) {
        ((float4*)&sX[0][0][0])[tid] = ((const float4*)xb)[tid];
    }
    float hprev = 0.0f;
    if (tid < H) sH[0][tid] = (_Float16)0.0f;
    __syncthreads();

    for (int t = 0; t < S; t++) {
        const int cur = t & 1;
        const int tw  = t & (CH - 1);
        const int c   = t >> 4;

        if (tw == 0) {
            if (c > 0) {
                const float4 v = ((const float4*)&sHo[(c - 1) & 1][0][0])[tid];
                ((float4*)(hob + (size_t)(c - 1) * CH * H))[tid] = v;
            }
            if (c + 1 < S / CH && tid < 64) {
                ((float4*)&sX[(c + 1) & 1][0][0])[tid] =
                    ((const float4*)(xb + (size_t)(c + 1) * CH * NI))[tid];
            }
        }

        const float4* hv = (const float4*)&sH[cur][0];
        float ar = 0.f, az = 0.f, ahn = 0.f;
#pragma unroll
        for (int i = 0; i < 4; i++) {
            const int f = (i + m) & 3;
            const float4 q = hv[4 * m + f];
            const h2 p0 = __builtin_bit_cast(h2, q.x);
            const h2 p1 = __builtin_bit_cast(h2, q.y);
            const h2 p2 = __builtin_bit_cast(h2, q.z);
            const h2 p3 = __builtin_bit_cast(h2, q.w);
            ar  = __builtin_amdgcn_fdot2(p0, whr[4*i+0], ar,  false);
            ar  = __builtin_amdgcn_fdot2(p1, whr[4*i+1], ar,  false);
            ar  = __builtin_amdgcn_fdot2(p2, whr[4*i+2], ar,  false);
            ar  = __builtin_amdgcn_fdot2(p3, whr[4*i+3], ar,  false);
            az  = __builtin_amdgcn_fdot2(p0, whz[4*i+0], az,  false);
            az  = __builtin_amdgcn_fdot2(p1, whz[4*i+1], az,  false);
            az  = __builtin_amdgcn_fdot2(p2, whz[4*i+2], az,  false);
            az  = __builtin_amdgcn_fdot2(p3, whz[4*i+3], az,  false);
            ahn = __builtin_amdgcn_fdot2(p0, whn[4*i+0], ahn, false);
            ahn = __builtin_amdgcn_fdot2(p1, whn[4*i+1], ahn, false);
            ahn = __builtin_amdgcn_fdot2(p2, whn[4*i+2], ahn, false);
            ahn = __builtin_amdgcn_fdot2(p3, whn[4*i+3], ahn, false);
        }
        const float4 xq = *(const float4*)&sX[c & 1][tw][4 * m];
        float ain = 0.f;
        ar  = fmaf(xq.x, wxr.x, ar);  ar  = fmaf(xq.y, wxr.y, ar);
        ar  = fmaf(xq.z, wxr.z, ar);  ar  = fmaf(xq.w, wxr.w, ar);
        az  = fmaf(xq.x, wxz.x, az);  az  = fmaf(xq.y, wxz.y, az);
        az  = fmaf(xq.z, wxz.z, az);  az  = fmaf(xq.w, wxz.w, az);
        ain = fmaf(xq.x, wxn.x, ain); ain = fmaf(xq.y, wxn.y, ain);
        ain = fmaf(xq.z, wxn.z, ain); ain = fmaf(xq.w, wxn.w, ain);

        const float vr  = quad_reduce(ar)  + b_r;
        const float vz  = quad_reduce(az)  + b_z;
        const float vhn = quad_reduce(ahn) + b_hn;
        const float vin = quad_reduce(ain) + b_in;

        const float r  = sigf(vr);
        const float z  = sigf(vz);
        const float n  = tanh_fast(vin + r * vhn);
        const float hn = n + z * (hprev - n);
        hprev = hn;
        if (m == 0) {
            sH[cur ^ 1][j]   = (_Float16)hn;
            sHo[c & 1][tw][j] = hn;
        }
        __syncthreads();
    }
    {
        const int c = S / CH - 1;
        const float4 v = ((const float4*)&sHo[c & 1][0][0])[tid];
        ((float4*)(hob + (size_t)c * CH * H))[tid] = v;
    }
}

// ---------------------------------------------------------------------------
// Layer 1: 64 blocks x 512 threads, s=4 split (round-4 layout) + chunked
// staging (round-5). Quad owns j=tid>>2; lane m owns k-quarter [32m,32m+32)
// of all 6 gate rows = 96 packed-h2 weight VGPRs; launch_bounds(512,2) gives
// a 256-VGPR cap so they stay resident. Reduction is quad-DPP only (NO
// ds_swizzle). h0 staged fp32->fp16 per 16-step chunk; h1 accumulated in LDS
// and flushed per chunk, overwriting h0 in place (2-chunk read-ahead).
// ---------------------------------------------------------------------------
__global__ __launch_bounds__(512, 2)
void gru_layer1(const float* __restrict__ w_ih, const float* __restrict__ w_hh,
                const float* __restrict__ b_ih, const float* __restrict__ b_hh,
                float* __restrict__ hbuf)
{
    __shared__ __align__(16) _Float16 sIn[2][CH][H];   // h0 chunks fp16 (16 KB)
    __shared__ __align__(16) _Float16 sH1[2][H];       // h1 state
    __shared__ __align__(16) float    sHo[2][CH][H];   // h1-out accum (16 KB)

    const int b   = blockIdx.x;
    const int tid = threadIdx.x;
    const int j   = tid >> 2;
    const int m   = tid & 3;

    // load-permuted weights: slot i holds sub-chunk f=(i+m)&3 (8 halves)
    h2 wir[16], wiz[16], win[16], whr[16], whz[16], whn[16];
#pragma unroll
    for (int i = 0; i < 4; i++) {
        const int f = (i + m) & 3;
        const int o = 32 * m + 8 * f;
        cvt8(w_ih + (size_t)j * H         + o, &wir[4 * i]);
        cvt8(w_ih + (size_t)(H + j) * H   + o, &wiz[4 * i]);
        cvt8(w_ih + (size_t)(2*H + j) * H + o, &win[4 * i]);
        cvt8(w_hh + (size_t)j * H         + o, &whr[4 * i]);
        cvt8(w_hh + (size_t)(H + j) * H   + o, &whz[4 * i]);
        cvt8(w_hh + (size_t)(2*H + j) * H + o, &whn[4 * i]);
    }
    const float b_r  = b_ih[j]       + b_hh[j];
    const float b_z  = b_ih[H + j]   + b_hh[H + j];
    const float b_in = b_ih[2*H + j];
    const float b_hn = b_hh[2*H + j];

    float* hb = hbuf + (size_t)b * S * H;

    {   // stage h0 chunk 0: 2048 floats = 512 lanes x float4 -> fp16
        const float4 v = ((const float4*)hb)[tid];
        h4v p; p[0] = (_Float16)v.x; p[1] = (_Float16)v.y;
               p[2] = (_Float16)v.z; p[3] = (_Float16)v.w;
        ((h4v*)&sIn[0][0][0])[tid] = p;
    }
    float hprev = 0.0f;
    if (tid < H) sH1[0][tid] = (_Float16)0.0f;
    __syncthreads();

    for (int t = 0; t < S; t++) {
        const int cur = t & 1;
        const int tw  = t & (CH - 1);
        const int c   = t >> 4;

        if (tw == 0) {
            if (c > 0) {   // flush h1 chunk c-1
                const float4 v = ((const float4*)&sHo[(c - 1) & 1][0][0])[tid];
                ((float4*)(hb + (size_t)(c - 1) * CH * H))[tid] = v;
            }
            if (c + 1 < S / CH) {   // stage h0 chunk c+1 (fp32 -> fp16)
                const float4 v = ((const float4*)(hb + (size_t)(c + 1) * CH * H))[tid];
                h4v p; p[0] = (_Float16)v.x; p[1] = (_Float16)v.y;
                       p[2] = (_Float16)v.z; p[3] = (_Float16)v.w;
                ((h4v*)&sIn[(c + 1) & 1][0][0])[tid] = p;
            }
        }

        const float4* A4 = (const float4*)&sIn[c & 1][tw][0];  // 16 float4 / row
        const float4* C4 = (const float4*)&sH1[cur][0];
        float ar = 0.f, az = 0.f, ain = 0.f, ahn = 0.f;
#pragma unroll
        for (int i = 0; i < 4; i++) {
            const int f = (i + m) & 3;                 // address-side stagger
            const float4 qa = A4[4 * m + f];
            const float4 qc = C4[4 * m + f];
            const h2 a0 = __builtin_bit_cast(h2, qa.x);
            const h2 a1 = __builtin_bit_cast(h2, qa.y);
            const h2 a2 = __builtin_bit_cast(h2, qa.z);
            const h2 a3 = __builtin_bit_cast(h2, qa.w);
            const h2 c0 = __builtin_bit_cast(h2, qc.x);
            const h2 c1 = __builtin_bit_cast(h2, qc.y);
            const h2 c2 = __builtin_bit_cast(h2, qc.z);
            const h2 c3 = __builtin_bit_cast(h2, qc.w);
            ar  = __builtin_amdgcn_fdot2(a0, wir[4*i+0], ar,  false);
            ar  = __builtin_amdgcn_fdot2(a1, wir[4*i+1], ar,  false);
            ar  = __builtin_amdgcn_fdot2(a2, wir[4*i+2], ar,  false);
            ar  = __builtin_amdgcn_fdot2(a3, wir[4*i+3], ar,  false);
            ar  = __builtin_amdgcn_fdot2(c0, whr[4*i+0], ar,  false);
            ar  = __builtin_amdgcn_fdot2(c1, whr[4*i+1], ar,  false);
            ar  = __builtin_amdgcn_fdot2(c2, whr[4*i+2], ar,  false);
            ar  = __builtin_amdgcn_fdot2(c3, whr[4*i+3], ar,  false);
            az  = __builtin_amdgcn_fdot2(a0, wiz[4*i+0], az,  false);
            az  = __builtin_amdgcn_fdot2(a1, wiz[4*i+1], az,  false);
            az  = __builtin_amdgcn_fdot2(a2, wiz[4*i+2], az,  false);
            az  = __builtin_amdgcn_fdot2(a3, wiz[4*i+3], az,  false);
            az  = __builtin_amdgcn_fdot2(c0, whz[4*i+0], az,  false);
            az  = __builtin_amdgcn_fdot2(c1, whz[4*i+1], az,  false);
            az  = __builtin_amdgcn_fdot2(c2, whz[4*i+2], az,  false);
            az  = __builtin_amdgcn_fdot2(c3, whz[4*i+3], az,  false);
            ain = __builtin_amdgcn_fdot2(a0, win[4*i+0], ain, false);
            ain = __builtin_amdgcn_fdot2(a1, win[4*i+1], ain, false);
            ain = __builtin_amdgcn_fdot2(a2, win[4*i+2], ain, false);
            ain = __builtin_amdgcn_fdot2(a3, win[4*i+3], ain, false);
            ahn = __builtin_amdgcn_fdot2(c0, whn[4*i+0], ahn, false);
            ahn = __builtin_amdgcn_fdot2(c1, whn[4*i+1], ahn, false);
            ahn = __builtin_amdgcn_fdot2(c2, whn[4*i+2], ahn, false);
            ahn = __builtin_amdgcn_fdot2(c3, whn[4*i+3], ahn, false);
        }
        const float vr  = quad_reduce(ar)  + b_r;
        const float vz  = quad_reduce(az)  + b_z;
        const float vin = quad_reduce(ain) + b_in;
        const float vhn = quad_reduce(ahn) + b_hn;

        const float r  = sigf(vr);
        const float z  = sigf(vz);
        const float n  = tanh_fast(vin + r * vhn);
        const float hn = n + z * (hprev - n);
        hprev = hn;
        if (m == 0) {
            sH1[cur ^ 1][j]   = (_Float16)hn;
            sHo[c & 1][tw][j] = hn;
        }
        __syncthreads();
    }
    {   // epilogue: flush last chunk
        const int c = S / CH - 1;
        const float4 v = ((const float4*)&sHo[c & 1][0][0])[tid];
        ((float4*)(hb + (size_t)c * CH * H))[tid] = v;
    }
}

// ---------------------------------------------------------------------------
// MLP head, batched over all B*S rows. One wave per block.
// ---------------------------------------------------------------------------
__global__ __launch_bounds__(64, 2)
void head_kernel(const float* __restrict__ h1, const float* __restrict__ x,
                 const float* __restrict__ w1, const float* __restrict__ b1,
                 const float* __restrict__ w2, const float* __restrict__ b2,
                 float* __restrict__ inc, int rows_per_blk)
{
    __shared__ float sC[2][F];
    const int lane = threadIdx.x;

    float wr[F];
#pragma unroll
    for (int f = 0; f < F; f++) wr[f] = w1[lane * F + f];
    const float b1v = b1[lane];
    const float w2v = w2[lane];
    const float b2v = b2[0];

    const int row0 = blockIdx.x * rows_per_blk;
    {
        const int r = row0;
        sC[0][lane]      = h1[(size_t)r * H + lane];
        sC[0][64 + lane] = h1[(size_t)r * H + 64 + lane];
        if (lane < NI) sC[0][H + lane] = x[(size_t)r * NI + lane];
    }
    __syncthreads();

    for (int i = 0; i < rows_per_blk; i++) {
        const int row = row0 + i;
        const int cur = i & 1;
        const int nxt = cur ^ 1;

        float p0 = 0.f, p1 = 0.f, p2 = 0.f;
        if (i + 1 < rows_per_blk) {
            const int rn = row + 1;
            p0 = h1[(size_t)rn * H + lane];
            p1 = h1[(size_t)rn * H + 64 + lane];
            if (lane < NI) p2 = x[(size_t)rn * NI + lane];
        }

        float acc = b1v;
#pragma unroll
        for (int f = 0; f < F; f++) acc += sC[cur][f] * wr[f];

        if (i + 1 < rows_per_blk) {
            sC[nxt][lane]      = p0;
            sC[nxt][64 + lane] = p1;
            if (lane < NI) sC[nxt][H + lane] = p2;
        }

        float v = fmaxf(acc, 0.0f) * w2v;
#pragma unroll
        for (int off = 32; off > 0; off >>= 1) v += __shfl_xor(v, off, 64);

        if (lane == 0) inc[row] = tanh_fast(v + b2v) * 0.125f;
        __syncthreads();
    }
}

// ---------------------------------------------------------------------------
// Inclusive cumsum over S per batch + initial offset. One block per batch.
// ---------------------------------------------------------------------------
__global__ __launch_bounds__(256)
void cumsum_kernel(const float* __restrict__ inc, const float* __restrict__ init,
                   float* __restrict__ out)
{
    __shared__ float sW[4];
    const int b = blockIdx.x;
    const int tid = threadIdx.x;
    const int lane = tid & 63;
    const int wid = tid >> 6;

    const float* ib = inc + (size_t)b * S;
    float v[16];
#pragma unroll
    for (int i = 0; i < 16; i++) v[i] = ib[tid * 16 + i];

    float run = 0.f;
#pragma unroll
    for (int i = 0; i < 16; i++) { run += v[i]; v[i] = run; }

    float t = run;
#pragma unroll
    for (int off = 1; off < 64; off <<= 1) {
        float u = __shfl_up(t, off, 64);
        if (lane >= off) t += u;
    }
    const float excl = t - run;
    if (lane == 63) sW[wid] = t;
    __syncthreads();

    float wo = 0.f;
#pragma unroll
    for (int w = 0; w < 4; w++) if (w < wid) wo += sW[w];

    const float prefix = wo + excl + init[0];
    float* ob = out + (size_t)b * S;
#pragma unroll
    for (int i = 0; i < 16; i++) ob[tid * 16 + i] = prefix + v[i];
}

// ---------------------------------------------------------------------------
extern "C" void kernel_launch(void* const* d_in, const int* in_sizes, int n_in,
                              void* d_out, int out_size, void* d_ws, size_t ws_size,
                              hipStream_t stream)
{
    const float* x     = (const float*)d_in[0];
    const float* w_ih0 = (const float*)d_in[1];
    const float* w_hh0 = (const float*)d_in[2];
    const float* b_ih0 = (const float*)d_in[3];
    const float* b_hh0 = (const float*)d_in[4];
    const float* w_ih1 = (const float*)d_in[5];
    const float* w_hh1 = (const float*)d_in[6];
    const float* b_ih1 = (const float*)d_in[7];
    const float* b_hh1 = (const float*)d_in[8];
    const float* w1    = (const float*)d_in[9];
    const float* b1    = (const float*)d_in[10];
    const float* w2    = (const float*)d_in[11];
    const float* b2    = (const float*)d_in[12];
    const float* init  = (const float*)d_in[13];
    float* out = (float*)d_out;

    float* hbuf   = (float*)d_ws;                 // B*S*H fp32 = 134 MB
    float* incbuf = hbuf + (size_t)B * S * H;     // B*S fp32  = 1 MB

    hipLaunchKernelGGL(gru_layer0, dim3(B), dim3(512), 0, stream,
                       x, w_ih0, w_hh0, b_ih0, b_hh0, hbuf);
    hipLaunchKernelGGL(gru_layer1, dim3(B), dim3(512), 0, stream,
                       w_ih1, w_hh1, b_ih1, b_hh1, hbuf);
    hipLaunchKernelGGL(head_kernel, dim3((B * S) / 128), dim3(64), 0, stream,
                       hbuf, x, w1, b1, w2, b2, incbuf, 128);
    hipLaunchKernelGGL(cumsum_kernel, dim3(B), dim3(256), 0, stream,
                       incbuf, init, out);
}

// Round 7
// 4758.340 us; speedup vs baseline: 1.6096x; 1.2230x over previous
//
#include <hip/hip_runtime.h>
#include <cmath>

#define B 64
#define S 4096
#define NI 16
#define H 128
#define F 144   // H + NI
#define CH 16   // timesteps per output-staging chunk
#define NCH (S / CH)

typedef _Float16 h2  __attribute__((ext_vector_type(2)));
typedef _Float16 h4v __attribute__((ext_vector_type(4)));

__device__ __forceinline__ float rcp_fast(float x) { return __builtin_amdgcn_rcpf(x); }
__device__ __forceinline__ float sigf(float x) {
    return rcp_fast(1.0f + __expf(-x));
}
// tanh(x) = 2*sigmoid(2x) - 1
__device__ __forceinline__ float tanh_fast(float x) {
    const float e = __expf(-2.0f * x);
    return fmaf(2.0f, rcp_fast(1.0f + e), -1.0f);
}
// all 4 lanes of each quad end with the 4-lane sum
__device__ __forceinline__ float quad_reduce(float v) {
    int t1 = __builtin_amdgcn_mov_dpp(__float_as_int(v), 0xB1, 0xf, 0xf, true); // xor 1
    v += __int_as_float(t1);
    int t2 = __builtin_amdgcn_mov_dpp(__float_as_int(v), 0x4E, 0xf, 0xf, true); // xor 2
    v += __int_as_float(t2);
    return v;
}
// both lanes of each pair end with the 2-lane sum
__device__ __forceinline__ float pair_reduce(float v) {
    int t1 = __builtin_amdgcn_mov_dpp(__float_as_int(v), 0xB1, 0xf, 0xf, true); // xor 1
    v += __int_as_float(t1);
    return v;
}
__device__ __forceinline__ h2 cvt2(float a, float b) {
    h2 r; r[0] = (_Float16)a; r[1] = (_Float16)b; return r;
}
// convert 8 consecutive fp32 -> 4 packed half2 regs
__device__ __forceinline__ void cvt8(const float* p, h2* w) {
    const float4 f0 = ((const float4*)p)[0];
    const float4 f1 = ((const float4*)p)[1];
    w[0] = cvt2(f0.x, f0.y); w[1] = cvt2(f0.z, f0.w);
    w[2] = cvt2(f1.x, f1.y); w[3] = cvt2(f1.z, f1.w);
}

// ---------------------------------------------------------------------------
// Fused 2-layer GRU. 64 blocks x 768 threads (12 waves, 3/SIMD).
//   waves 0-3  (tid<256):  layer 0, pair owns j=tid>>1, lane m=tid&1 owns
//                          h-cols [64m,64m+64) + x-cols [8m,8m+8). Computes
//                          h0[k] at iteration k.
//   waves 4-11 (tid>=256): layer 1, quad owns j, lane m owns k-quarter
//                          [32m,32m+32) of all 6 gate rows (round-6 body).
//                          Computes h1[k-1] at iteration k (1-step pipeline).
// h0 never touches global memory: double-buffered fp16 LDS state written by
// L0, read by both groups next iteration. One barrier per iteration.
// h1 accumulated in LDS, flushed to global every CH steps.
// ---------------------------------------------------------------------------
__global__ __launch_bounds__(768, 3)
void gru_fused(const float* __restrict__ x,
               const float* __restrict__ w_ih0, const float* __restrict__ w_hh0,
               const float* __restrict__ b_ih0, const float* __restrict__ b_hh0,
               const float* __restrict__ w_ih1, const float* __restrict__ w_hh1,
               const float* __restrict__ b_ih1, const float* __restrict__ b_hh1,
               float* __restrict__ h_out)
{
    __shared__ __align__(16) _Float16 sH0[2][H];      // h0 state ping-pong
    __shared__ __align__(16) _Float16 sH1[2][H];      // h1 state ping-pong
    __shared__ __align__(16) _Float16 sX[2][CH][NI];  // x chunks (fp16, 1 KB)
    __shared__ __align__(16) float    sHo[2][CH][H];  // h1 out accum (16 KB)

    const int b    = blockIdx.x;
    const int tid  = threadIdx.x;
    const bool isL0 = (tid < 256);

    // unified weight file: L0 uses wreg[0..95] as 3 gates x 32 h2 (64 halves);
    // L1 uses wreg[0..95] as 6 gates x 16 h2 (32 halves). wx is L0-only.
    h2 wreg[96];
    h2 wx[12];
    float b_r, b_z, b_in, b_hn;
    int j, m;

    if (isL0) {
        j = tid >> 1; m = tid & 1;
#pragma unroll
        for (int ii = 0; ii < 8; ii++) {
            cvt8(w_hh0 + (size_t)j * H         + 64 * m + 8 * ii, &wreg[4 * ii]);
            cvt8(w_hh0 + (size_t)(H + j) * H   + 64 * m + 8 * ii, &wreg[32 + 4 * ii]);
            cvt8(w_hh0 + (size_t)(2*H + j) * H + 64 * m + 8 * ii, &wreg[64 + 4 * ii]);
        }
        cvt8(w_ih0 + (size_t)j * NI         + 8 * m, &wx[0]);
        cvt8(w_ih0 + (size_t)(H + j) * NI   + 8 * m, &wx[4]);
        cvt8(w_ih0 + (size_t)(2*H + j) * NI + 8 * m, &wx[8]);
        b_r  = b_ih0[j]       + b_hh0[j];
        b_z  = b_ih0[H + j]   + b_hh0[H + j];
        b_in = b_ih0[2*H + j];
        b_hn = b_hh0[2*H + j];
    } else {
        const int tid1 = tid - 256;
        j = tid1 >> 2; m = tid1 & 3;
        // load-permuted: slot i holds sub-chunk f=(i+m)&3 (compile-time reg idx)
#pragma unroll
        for (int i = 0; i < 4; i++) {
            const int f = (i + m) & 3;
            const int o = 32 * m + 8 * f;
            cvt8(w_ih1 + (size_t)j * H         + o, &wreg[ 0 + 4 * i]);
            cvt8(w_ih1 + (size_t)(H + j) * H   + o, &wreg[16 + 4 * i]);
            cvt8(w_ih1 + (size_t)(2*H + j) * H + o, &wreg[32 + 4 * i]);
            cvt8(w_hh1 + (size_t)j * H         + o, &wreg[48 + 4 * i]);
            cvt8(w_hh1 + (size_t)(H + j) * H   + o, &wreg[64 + 4 * i]);
            cvt8(w_hh1 + (size_t)(2*H + j) * H + o, &wreg[80 + 4 * i]);
        }
        b_r  = b_ih1[j]       + b_hh1[j];
        b_z  = b_ih1[H + j]   + b_hh1[H + j];
        b_in = b_ih1[2*H + j];
        b_hn = b_hh1[2*H + j];
    }

    const float* xb = x + (size_t)b * S * NI;
    float*       hb = h_out + (size_t)b * S * H;

    // prologue: zero states; stage x chunk 0 to LDS; chunk 1 into regs
    float4 xreg = {0.f, 0.f, 0.f, 0.f};
    if (tid < H) { sH0[0][tid] = (_Float16)0.0f; sH1[1][tid] = (_Float16)0.0f; }
    if (tid < 64) {
        const float4 v = ((const float4*)xb)[tid];
        h4v p; p[0] = (_Float16)v.x; p[1] = (_Float16)v.y;
               p[2] = (_Float16)v.z; p[3] = (_Float16)v.w;
        ((h4v*)&sX[0][0][0])[tid] = p;
        xreg = ((const float4*)(xb + CH * NI))[tid];
    }
    float hprev = 0.0f;
    __syncthreads();

    for (int k = 0; k <= S; k++) {
        const int cur = k & 1;

        if (isL0) {
            if (k < S) {
                const int c0  = k >> 4;
                const int tw0 = k & (CH - 1);

                if (tw0 == 0 && tid < 64) {
                    const int cn = c0 + 1;          // chunk now moving reg->LDS
                    if (cn < NCH) {
                        h4v p; p[0] = (_Float16)xreg.x; p[1] = (_Float16)xreg.y;
                               p[2] = (_Float16)xreg.z; p[3] = (_Float16)xreg.w;
                        ((h4v*)&sX[cn & 1][0][0])[tid] = p;
                        if (cn + 1 < NCH)
                            xreg = ((const float4*)(xb + (size_t)(cn + 1) * CH * NI))[tid];
                    }
                }

                const float4* hv = (const float4*)&sH0[cur][0];   // 16 f4/row
                float ar = 0.f, az = 0.f, ahn = 0.f;
#pragma unroll
                for (int i = 0; i < 8; i++) {
                    const float4 q = hv[8 * m + i];
                    const h2 p0 = __builtin_bit_cast(h2, q.x);
                    const h2 p1 = __builtin_bit_cast(h2, q.y);
                    const h2 p2 = __builtin_bit_cast(h2, q.z);
                    const h2 p3 = __builtin_bit_cast(h2, q.w);
                    ar  = __builtin_amdgcn_fdot2(p0, wreg[4*i+0],    ar,  false);
                    ar  = __builtin_amdgcn_fdot2(p1, wreg[4*i+1],    ar,  false);
                    ar  = __builtin_amdgcn_fdot2(p2, wreg[4*i+2],    ar,  false);
                    ar  = __builtin_amdgcn_fdot2(p3, wreg[4*i+3],    ar,  false);
                    az  = __builtin_amdgcn_fdot2(p0, wreg[32+4*i+0], az,  false);
                    az  = __builtin_amdgcn_fdot2(p1, wreg[32+4*i+1], az,  false);
                    az  = __builtin_amdgcn_fdot2(p2, wreg[32+4*i+2], az,  false);
                    az  = __builtin_amdgcn_fdot2(p3, wreg[32+4*i+3], az,  false);
                    ahn = __builtin_amdgcn_fdot2(p0, wreg[64+4*i+0], ahn, false);
                    ahn = __builtin_amdgcn_fdot2(p1, wreg[64+4*i+1], ahn, false);
                    ahn = __builtin_amdgcn_fdot2(p2, wreg[64+4*i+2], ahn, false);
                    ahn = __builtin_amdgcn_fdot2(p3, wreg[64+4*i+3], ahn, false);
                }
                const float4 xq = *(const float4*)&sX[c0 & 1][tw0][8 * m];
                const h2 x0 = __builtin_bit_cast(h2, xq.x);
                const h2 x1 = __builtin_bit_cast(h2, xq.y);
                const h2 x2 = __builtin_bit_cast(h2, xq.z);
                const h2 x3 = __builtin_bit_cast(h2, xq.w);
                float ain = 0.f;
                ar  = __builtin_amdgcn_fdot2(x0, wx[0],  ar,  false);
                ar  = __builtin_amdgcn_fdot2(x1, wx[1],  ar,  false);
                ar  = __builtin_amdgcn_fdot2(x2, wx[2],  ar,  false);
                ar  = __builtin_amdgcn_fdot2(x3, wx[3],  ar,  false);
                az  = __builtin_amdgcn_fdot2(x0, wx[4],  az,  false);
                az  = __builtin_amdgcn_fdot2(x1, wx[5],  az,  false);
                az  = __builtin_amdgcn_fdot2(x2, wx[6],  az,  false);
                az  = __builtin_amdgcn_fdot2(x3, wx[7],  az,  false);
                ain = __builtin_amdgcn_fdot2(x0, wx[8],  ain, false);
                ain = __builtin_amdgcn_fdot2(x1, wx[9],  ain, false);
                ain = __builtin_amdgcn_fdot2(x2, wx[10], ain, false);
                ain = __builtin_amdgcn_fdot2(x3, wx[11], ain, false);

                const float vr  = pair_reduce(ar)  + b_r;
                const float vz  = pair_reduce(az)  + b_z;
                const float vhn = pair_reduce(ahn) + b_hn;
                const float vin = pair_reduce(ain) + b_in;

                const float r  = sigf(vr);
                const float z  = sigf(vz);
                const float n  = tanh_fast(vin + r * vhn);
                const float hn = n + z * (hprev - n);
                hprev = hn;
                if (m == 0) sH0[cur ^ 1][j] = (_Float16)hn;
            }
        } else {
            if (k >= 1) {
                const int t   = k - 1;
                const int ct  = t >> 4;
                const int twt = t & (CH - 1);

                const float4* A4 = (const float4*)&sH0[cur][0];   // h0[t]
                const float4* C4 = (const float4*)&sH1[cur][0];   // h1[t-1]
                float ar = 0.f, az = 0.f, ain = 0.f, ahn = 0.f;
#pragma unroll
                for (int i = 0; i < 4; i++) {
                    const int f = (i + m) & 3;                    // addr stagger
                    const float4 qa = A4[4 * m + f];
                    const float4 qc = C4[4 * m + f];
                    const h2 a0 = __builtin_bit_cast(h2, qa.x);
                    const h2 a1 = __builtin_bit_cast(h2, qa.y);
                    const h2 a2 = __builtin_bit_cast(h2, qa.z);
                    const h2 a3 = __builtin_bit_cast(h2, qa.w);
                    const h2 c0 = __builtin_bit_cast(h2, qc.x);
                    const h2 c1 = __builtin_bit_cast(h2, qc.y);
                    const h2 c2 = __builtin_bit_cast(h2, qc.z);
                    const h2 c3 = __builtin_bit_cast(h2, qc.w);
                    ar  = __builtin_amdgcn_fdot2(a0, wreg[ 0+4*i+0], ar,  false);
                    ar  = __builtin_amdgcn_fdot2(a1, wreg[ 0+4*i+1], ar,  false);
                    ar  = __builtin_amdgcn_fdot2(a2, wreg[ 0+4*i+2], ar,  false);
                    ar  = __builtin_amdgcn_fdot2(a3, wreg[ 0+4*i+3], ar,  false);
                    ar  = __builtin_amdgcn_fdot2(c0, wreg[48+4*i+0], ar,  false);
                    ar  = __builtin_amdgcn_fdot2(c1, wreg[48+4*i+1], ar,  false);
                    ar  = __builtin_amdgcn_fdot2(c2, wreg[48+4*i+2], ar,  false);
                    ar  = __builtin_amdgcn_fdot2(c3, wreg[48+4*i+3], ar,  false);
                    az  = __builtin_amdgcn_fdot2(a0, wreg[16+4*i+0], az,  false);
                    az  = __builtin_amdgcn_fdot2(a1, wreg[16+4*i+1], az,  false);
                    az  = __builtin_amdgcn_fdot2(a2, wreg[16+4*i+2], az,  false);
                    az  = __builtin_amdgcn_fdot2(a3, wreg[16+4*i+3], az,  false);
                    az  = __builtin_amdgcn_fdot2(c0, wreg[64+4*i+0], az,  false);
                    az  = __builtin_amdgcn_fdot2(c1, wreg[64+4*i+1], az,  false);
                    az  = __builtin_amdgcn_fdot2(c2, wreg[64+4*i+2], az,  false);
                    az  = __builtin_amdgcn_fdot2(c3, wreg[64+4*i+3], az,  false);
                    ain = __builtin_amdgcn_fdot2(a0, wreg[32+4*i+0], ain, false);
                    ain = __builtin_amdgcn_fdot2(a1, wreg[32+4*i+1], ain, false);
                    ain = __builtin_amdgcn_fdot2(a2, wreg[32+4*i+2], ain, false);
                    ain = __builtin_amdgcn_fdot2(a3, wreg[32+4*i+3], ain, false);
                    ahn = __builtin_amdgcn_fdot2(c0, wreg[80+4*i+0], ahn, false);
                    ahn = __builtin_amdgcn_fdot2(c1, wreg[80+4*i+1], ahn, false);
                    ahn = __builtin_amdgcn_fdot2(c2, wreg[80+4*i+2], ahn, false);
                    ahn = __builtin_amdgcn_fdot2(c3, wreg[80+4*i+3], ahn, false);
                }
                const float vr  = quad_reduce(ar)  + b_r;
                const float vz  = quad_reduce(az)  + b_z;
                const float vin = quad_reduce(ain) + b_in;
                const float vhn = quad_reduce(ahn) + b_hn;

                const float r  = sigf(vr);
                const float z  = sigf(vz);
                const float n  = tanh_fast(vin + r * vhn);
                const float hn = n + z * (hprev - n);
                hprev = hn;
                if (m == 0) {
                    sH1[cur ^ 1][j]    = (_Float16)hn;
                    sHo[ct & 1][twt][j] = hn;
                }
                // flush completed output chunk (k = 16*cp + 17)
                if ((k & (CH - 1)) == 1 && k >= CH + 1) {
                    const int cp  = (k >> 4) - 1;
                    const int idx = tid - 256;           // 512 lanes x float4
                    const float4 v = ((const float4*)&sHo[cp & 1][0][0])[idx];
                    ((float4*)(hb + (size_t)cp * CH * H))[idx] = v;
                }
            }
        }
        __syncthreads();
    }

    // epilogue: flush last chunk (cp = NCH-1, buffer 1)
    if (!isL0) {
        const int cp  = NCH - 1;
        const int idx = tid - 256;
        const float4 v = ((const float4*)&sHo[cp & 1][0][0])[idx];
        ((float4*)(hb + (size_t)cp * CH * H))[idx] = v;
    }
}

// ---------------------------------------------------------------------------
// MLP head, batched over all B*S rows. One wave per block.
// ---------------------------------------------------------------------------
__global__ __launch_bounds__(64, 2)
void head_kernel(const float* __restrict__ h1, const float* __restrict__ x,
                 const float* __restrict__ w1, const float* __restrict__ b1,
                 const float* __restrict__ w2, const float* __restrict__ b2,
                 float* __restrict__ inc, int rows_per_blk)
{
    __shared__ float sC[2][F];
    const int lane = threadIdx.x;

    float wr[F];
#pragma unroll
    for (int f = 0; f < F; f++) wr[f] = w1[lane * F + f];
    const float b1v = b1[lane];
    const float w2v = w2[lane];
    const float b2v = b2[0];

    const int row0 = blockIdx.x * rows_per_blk;
    {
        const int r = row0;
        sC[0][lane]      = h1[(size_t)r * H + lane];
        sC[0][64 + lane] = h1[(size_t)r * H + 64 + lane];
        if (lane < NI) sC[0][H + lane] = x[(size_t)r * NI + lane];
    }
    __syncthreads();

    for (int i = 0; i < rows_per_blk; i++) {
        const int row = row0 + i;
        const int cur = i & 1;
        const int nxt = cur ^ 1;

        float p0 = 0.f, p1 = 0.f, p2 = 0.f;
        if (i + 1 < rows_per_blk) {
            const int rn = row + 1;
            p0 = h1[(size_t)rn * H + lane];
            p1 = h1[(size_t)rn * H + 64 + lane];
            if (lane < NI) p2 = x[(size_t)rn * NI + lane];
        }

        float acc = b1v;
#pragma unroll
        for (int f = 0; f < F; f++) acc += sC[cur][f] * wr[f];

        if (i + 1 < rows_per_blk) {
            sC[nxt][lane]      = p0;
            sC[nxt][64 + lane] = p1;
            if (lane < NI) sC[nxt][H + lane] = p2;
        }

        float v = fmaxf(acc, 0.0f) * w2v;
#pragma unroll
        for (int off = 32; off > 0; off >>= 1) v += __shfl_xor(v, off, 64);

        if (lane == 0) inc[row] = tanh_fast(v + b2v) * 0.125f;
        __syncthreads();
    }
}

// ---------------------------------------------------------------------------
// Inclusive cumsum over S per batch + initial offset. One block per batch.
// ---------------------------------------------------------------------------
__global__ __launch_bounds__(256)
void cumsum_kernel(const float* __restrict__ inc, const float* __restrict__ init,
                   float* __restrict__ out)
{
    __shared__ float sW[4];
    const int b = blockIdx.x;
    const int tid = threadIdx.x;
    const int lane = tid & 63;
    const int wid = tid >> 6;

    const float* ib = inc + (size_t)b * S;
    float v[16];
#pragma unroll
    for (int i = 0; i < 16; i++) v[i] = ib[tid * 16 + i];

    float run = 0.f;
#pragma unroll
    for (int i = 0; i < 16; i++) { run += v[i]; v[i] = run; }

    float t = run;
#pragma unroll
    for (int off = 1; off < 64; off <<= 1) {
        float u = __shfl_up(t, off, 64);
        if (lane >= off) t += u;
    }
    const float excl = t - run;
    if (lane == 63) sW[wid] = t;
    __syncthreads();

    float wo = 0.f;
#pragma unroll
    for (int w = 0; w < 4; w++) if (w < wid) wo += sW[w];

    const float prefix = wo + excl + init[0];
    float* ob = out + (size_t)b * S;
#pragma unroll
    for (int i = 0; i < 16; i++) ob[tid * 16 + i] = prefix + v[i];
}

// ---------------------------------------------------------------------------
extern "C" void kernel_launch(void* const* d_in, const int* in_sizes, int n_in,
                              void* d_out, int out_size, void* d_ws, size_t ws_size,
                              hipStream_t stream)
{
    const float* x     = (const float*)d_in[0];
    const float* w_ih0 = (const float*)d_in[1];
    const float* w_hh0 = (const float*)d_in[2];
    const float* b_ih0 = (const float*)d_in[3];
    const float* b_hh0 = (const float*)d_in[4];
    const float* w_ih1 = (const float*)d_in[5];
    const float* w_hh1 = (const float*)d_in[6];
    const float* b_ih1 = (const float*)d_in[7];
    const float* b_hh1 = (const float*)d_in[8];
    const float* w1    = (const float*)d_in[9];
    const float* b1    = (const float*)d_in[10];
    const float* w2    = (const float*)d_in[11];
    const float* b2    = (const float*)d_in[12];
    const float* init  = (const float*)d_in[13];
    float* out = (float*)d_out;

    float* hbuf   = (float*)d_ws;                 // B*S*H fp32 = 134 MB (h1 only)
    float* incbuf = hbuf + (size_t)B * S * H;     // B*S fp32  = 1 MB

    hipLaunchKernelGGL(gru_fused, dim3(B), dim3(768), 0, stream,
                       x, w_ih0, w_hh0, b_ih0, b_hh0,
                       w_ih1, w_hh1, b_ih1, b_hh1, hbuf);
    hipLaunchKernelGGL(head_kernel, dim3((B * S) / 128), dim3(64), 0, stream,
                       hbuf, x, w1, b1, w2, b2, incbuf, 128);
    hipLaunchKernelGGL(cumsum_kernel, dim3(B), dim3(256), 0, stream,
                       incbuf, init, out);
}

// Round 8
// 4750.932 us; speedup vs baseline: 1.6121x; 1.0016x over previous
//
#include <hip/hip_runtime.h>
#include <cmath>

#define B 64
#define S 4096
#define NI 16
#define H 128
#define F 144   // H + NI
#define CH 16   // timesteps per output-staging chunk
#define NCH (S / CH)

typedef _Float16 h2  __attribute__((ext_vector_type(2)));
typedef _Float16 h4v __attribute__((ext_vector_type(4)));

__device__ __forceinline__ float rcp_fast(float x) { return __builtin_amdgcn_rcpf(x); }
__device__ __forceinline__ float sigf(float x) {
    return rcp_fast(1.0f + __expf(-x));
}
// tanh(x) = 2*sigmoid(2x) - 1
__device__ __forceinline__ float tanh_fast(float x) {
    const float e = __expf(-2.0f * x);
    return fmaf(2.0f, rcp_fast(1.0f + e), -1.0f);
}
// all 4 lanes of each quad end with the 4-lane sum
__device__ __forceinline__ float quad_reduce(float v) {
    int t1 = __builtin_amdgcn_mov_dpp(__float_as_int(v), 0xB1, 0xf, 0xf, true); // xor 1
    v += __int_as_float(t1);
    int t2 = __builtin_amdgcn_mov_dpp(__float_as_int(v), 0x4E, 0xf, 0xf, true); // xor 2
    v += __int_as_float(t2);
    return v;
}
// both lanes of each pair end with the 2-lane sum
__device__ __forceinline__ float pair_reduce(float v) {
    int t1 = __builtin_amdgcn_mov_dpp(__float_as_int(v), 0xB1, 0xf, 0xf, true); // xor 1
    v += __int_as_float(t1);
    return v;
}
__device__ __forceinline__ h2 cvt2(float a, float b) {
    h2 r; r[0] = (_Float16)a; r[1] = (_Float16)b; return r;
}
// convert 8 consecutive fp32 -> 4 packed half2 regs
__device__ __forceinline__ void cvt8(const float* p, h2* w) {
    const float4 f0 = ((const float4*)p)[0];
    const float4 f1 = ((const float4*)p)[1];
    w[0] = cvt2(f0.x, f0.y); w[1] = cvt2(f0.z, f0.w);
    w[2] = cvt2(f1.x, f1.y); w[3] = cvt2(f1.z, f1.w);
}
// Opaque register pin: the value passes through an empty asm, so the compiler
// cannot rematerialize/sink the load that produced it — it MUST stay in a VGPR.
__device__ __forceinline__ void pin_h2(h2& v) {
    int t = __builtin_bit_cast(int, v);
    asm volatile("" : "+v"(t));
    v = __builtin_bit_cast(h2, t);
}
__device__ __forceinline__ void pin_f(float& v) {
    asm volatile("" : "+v"(v));
}

// ---------------------------------------------------------------------------
// Fused 2-layer GRU. 64 blocks x 768 threads (12 waves, 3/SIMD).
//   waves 0-3  (tid<256):  layer 0, pair owns j=tid>>1, lane m=tid&1 owns
//                          h-cols [64m,64m+64) + x-cols [8m,8m+8).
//   waves 4-11 (tid>=256): layer 1, quad owns j, lane m owns k-quarter
//                          [32m,32m+32) of all 6 gate rows.
// 1-step pipeline through double-buffered fp16 LDS h0 state; one barrier per
// iteration; h1 accumulated in LDS, flushed every CH steps. Weights pinned
// in VGPRs via asm barrier (VGPR_Count=84 in round 7 proved they were sunk).
// ---------------------------------------------------------------------------
__global__ __launch_bounds__(768, 3)
void gru_fused(const float* __restrict__ x,
               const float* __restrict__ w_ih0, const float* __restrict__ w_hh0,
               const float* __restrict__ b_ih0, const float* __restrict__ b_hh0,
               const float* __restrict__ w_ih1, const float* __restrict__ w_hh1,
               const float* __restrict__ b_ih1, const float* __restrict__ b_hh1,
               float* __restrict__ h_out)
{
    __shared__ __align__(16) _Float16 sH0[2][H];      // h0 state ping-pong
    __shared__ __align__(16) _Float16 sH1[2][H];      // h1 state ping-pong
    __shared__ __align__(16) _Float16 sX[2][CH][NI];  // x chunks (fp16, 1 KB)
    __shared__ __align__(16) float    sHo[2][CH][H];  // h1 out accum (16 KB)

    const int b    = blockIdx.x;
    const int tid  = threadIdx.x;
    const bool isL0 = (tid < 256);

    // unified weight file: L0 = 3 gates x 32 h2; L1 = 6 gates x 16 h2.
    h2 wreg[96];
    h2 wx[12];
    float b_r, b_z, b_in, b_hn;
    int j, m;

    if (isL0) {
        j = tid >> 1; m = tid & 1;
#pragma unroll
        for (int ii = 0; ii < 8; ii++) {
            cvt8(w_hh0 + (size_t)j * H         + 64 * m + 8 * ii, &wreg[4 * ii]);
            cvt8(w_hh0 + (size_t)(H + j) * H   + 64 * m + 8 * ii, &wreg[32 + 4 * ii]);
            cvt8(w_hh0 + (size_t)(2*H + j) * H + 64 * m + 8 * ii, &wreg[64 + 4 * ii]);
        }
        cvt8(w_ih0 + (size_t)j * NI         + 8 * m, &wx[0]);
        cvt8(w_ih0 + (size_t)(H + j) * NI   + 8 * m, &wx[4]);
        cvt8(w_ih0 + (size_t)(2*H + j) * NI + 8 * m, &wx[8]);
        b_r  = b_ih0[j]       + b_hh0[j];
        b_z  = b_ih0[H + j]   + b_hh0[H + j];
        b_in = b_ih0[2*H + j];
        b_hn = b_hh0[2*H + j];
    } else {
        const int tid1 = tid - 256;
        j = tid1 >> 2; m = tid1 & 3;
        // load-permuted: slot i holds sub-chunk f=(i+m)&3 (compile-time reg idx)
#pragma unroll
        for (int i = 0; i < 4; i++) {
            const int f = (i + m) & 3;
            const int o = 32 * m + 8 * f;
            cvt8(w_ih1 + (size_t)j * H         + o, &wreg[ 0 + 4 * i]);
            cvt8(w_ih1 + (size_t)(H + j) * H   + o, &wreg[16 + 4 * i]);
            cvt8(w_ih1 + (size_t)(2*H + j) * H + o, &wreg[32 + 4 * i]);
            cvt8(w_hh1 + (size_t)j * H         + o, &wreg[48 + 4 * i]);
            cvt8(w_hh1 + (size_t)(H + j) * H   + o, &wreg[64 + 4 * i]);
            cvt8(w_hh1 + (size_t)(2*H + j) * H + o, &wreg[80 + 4 * i]);
        }
        b_r  = b_ih1[j]       + b_hh1[j];
        b_z  = b_ih1[H + j]   + b_hh1[H + j];
        b_in = b_ih1[2*H + j];
        b_hn = b_hh1[2*H + j];
    }
    // pin everything loop-invariant into VGPRs (defeats load sinking)
#pragma unroll
    for (int i = 0; i < 96; i++) pin_h2(wreg[i]);
#pragma unroll
    for (int i = 0; i < 12; i++) pin_h2(wx[i]);
    pin_f(b_r); pin_f(b_z); pin_f(b_in); pin_f(b_hn);

    const float* xb = x + (size_t)b * S * NI;
    float*       hb = h_out + (size_t)b * S * H;

    // prologue: zero states; stage x chunk 0 to LDS; chunk 1 into regs
    float4 xreg = {0.f, 0.f, 0.f, 0.f};
    if (tid < H) { sH0[0][tid] = (_Float16)0.0f; sH1[1][tid] = (_Float16)0.0f; }
    if (tid < 64) {
        const float4 v = ((const float4*)xb)[tid];
        h4v p; p[0] = (_Float16)v.x; p[1] = (_Float16)v.y;
               p[2] = (_Float16)v.z; p[3] = (_Float16)v.w;
        ((h4v*)&sX[0][0][0])[tid] = p;
        xreg = ((const float4*)(xb + CH * NI))[tid];
    }
    float hprev = 0.0f;
    __syncthreads();

    for (int k = 0; k <= S; k++) {
        const int cur = k & 1;

        if (isL0) {
            if (k < S) {
                const int c0  = k >> 4;
                const int tw0 = k & (CH - 1);

                if (tw0 == 0 && tid < 64) {
                    const int cn = c0 + 1;          // chunk now moving reg->LDS
                    if (cn < NCH) {
                        h4v p; p[0] = (_Float16)xreg.x; p[1] = (_Float16)xreg.y;
                               p[2] = (_Float16)xreg.z; p[3] = (_Float16)xreg.w;
                        ((h4v*)&sX[cn & 1][0][0])[tid] = p;
                        if (cn + 1 < NCH)
                            xreg = ((const float4*)(xb + (size_t)(cn + 1) * CH * NI))[tid];
                    }
                }

                const float4* hv = (const float4*)&sH0[cur][0];   // 16 f4/row
                float ar = 0.f, az = 0.f, ahn = 0.f;
#pragma unroll
                for (int i = 0; i < 8; i++) {
                    const float4 q = hv[8 * m + i];
                    const h2 p0 = __builtin_bit_cast(h2, q.x);
                    const h2 p1 = __builtin_bit_cast(h2, q.y);
                    const h2 p2 = __builtin_bit_cast(h2, q.z);
                    const h2 p3 = __builtin_bit_cast(h2, q.w);
                    ar  = __builtin_amdgcn_fdot2(p0, wreg[4*i+0],    ar,  false);
                    ar  = __builtin_amdgcn_fdot2(p1, wreg[4*i+1],    ar,  false);
                    ar  = __builtin_amdgcn_fdot2(p2, wreg[4*i+2],    ar,  false);
                    ar  = __builtin_amdgcn_fdot2(p3, wreg[4*i+3],    ar,  false);
                    az  = __builtin_amdgcn_fdot2(p0, wreg[32+4*i+0], az,  false);
                    az  = __builtin_amdgcn_fdot2(p1, wreg[32+4*i+1], az,  false);
                    az  = __builtin_amdgcn_fdot2(p2, wreg[32+4*i+2], az,  false);
                    az  = __builtin_amdgcn_fdot2(p3, wreg[32+4*i+3], az,  false);
                    ahn = __builtin_amdgcn_fdot2(p0, wreg[64+4*i+0], ahn, false);
                    ahn = __builtin_amdgcn_fdot2(p1, wreg[64+4*i+1], ahn, false);
                    ahn = __builtin_amdgcn_fdot2(p2, wreg[64+4*i+2], ahn, false);
                    ahn = __builtin_amdgcn_fdot2(p3, wreg[64+4*i+3], ahn, false);
                }
                const float4 xq = *(const float4*)&sX[c0 & 1][tw0][8 * m];
                const h2 x0 = __builtin_bit_cast(h2, xq.x);
                const h2 x1 = __builtin_bit_cast(h2, xq.y);
                const h2 x2 = __builtin_bit_cast(h2, xq.z);
                const h2 x3 = __builtin_bit_cast(h2, xq.w);
                float ain = 0.f;
                ar  = __builtin_amdgcn_fdot2(x0, wx[0],  ar,  false);
                ar  = __builtin_amdgcn_fdot2(x1, wx[1],  ar,  false);
                ar  = __builtin_amdgcn_fdot2(x2, wx[2],  ar,  false);
                ar  = __builtin_amdgcn_fdot2(x3, wx[3],  ar,  false);
                az  = __builtin_amdgcn_fdot2(x0, wx[4],  az,  false);
                az  = __builtin_amdgcn_fdot2(x1, wx[5],  az,  false);
                az  = __builtin_amdgcn_fdot2(x2, wx[6],  az,  false);
                az  = __builtin_amdgcn_fdot2(x3, wx[7],  az,  false);
                ain = __builtin_amdgcn_fdot2(x0, wx[8],  ain, false);
                ain = __builtin_amdgcn_fdot2(x1, wx[9],  ain, false);
                ain = __builtin_amdgcn_fdot2(x2, wx[10], ain, false);
                ain = __builtin_amdgcn_fdot2(x3, wx[11], ain, false);

                const float vr  = pair_reduce(ar)  + b_r;
                const float vz  = pair_reduce(az)  + b_z;
                const float vhn = pair_reduce(ahn) + b_hn;
                const float vin = pair_reduce(ain) + b_in;

                const float r  = sigf(vr);
                const float z  = sigf(vz);
                const float n  = tanh_fast(vin + r * vhn);
                const float hn = n + z * (hprev - n);
                hprev = hn;
                if (m == 0) sH0[cur ^ 1][j] = (_Float16)hn;
            }
        } else {
            if (k >= 1) {
                const int t   = k - 1;
                const int ct  = t >> 4;
                const int twt = t & (CH - 1);

                const float4* A4 = (const float4*)&sH0[cur][0];   // h0[t]
                const float4* C4 = (const float4*)&sH1[cur][0];   // h1[t-1]
                float ar = 0.f, az = 0.f, ain = 0.f, ahn = 0.f;
#pragma unroll
                for (int i = 0; i < 4; i++) {
                    const int f = (i + m) & 3;                    // addr stagger
                    const float4 qa = A4[4 * m + f];
                    const float4 qc = C4[4 * m + f];
                    const h2 a0 = __builtin_bit_cast(h2, qa.x);
                    const h2 a1 = __builtin_bit_cast(h2, qa.y);
                    const h2 a2 = __builtin_bit_cast(h2, qa.z);
                    const h2 a3 = __builtin_bit_cast(h2, qa.w);
                    const h2 c0 = __builtin_bit_cast(h2, qc.x);
                    const h2 c1 = __builtin_bit_cast(h2, qc.y);
                    const h2 c2 = __builtin_bit_cast(h2, qc.z);
                    const h2 c3 = __builtin_bit_cast(h2, qc.w);
                    ar  = __builtin_amdgcn_fdot2(a0, wreg[ 0+4*i+0], ar,  false);
                    ar  = __builtin_amdgcn_fdot2(a1, wreg[ 0+4*i+1], ar,  false);
                    ar  = __builtin_amdgcn_fdot2(a2, wreg[ 0+4*i+2], ar,  false);
                    ar  = __builtin_amdgcn_fdot2(a3, wreg[ 0+4*i+3], ar,  false);
                    ar  = __builtin_amdgcn_fdot2(c0, wreg[48+4*i+0], ar,  false);
                    ar  = __builtin_amdgcn_fdot2(c1, wreg[48+4*i+1], ar,  false);
                    ar  = __builtin_amdgcn_fdot2(c2, wreg[48+4*i+2], ar,  false);
                    ar  = __builtin_amdgcn_fdot2(c3, wreg[48+4*i+3], ar,  false);
                    az  = __builtin_amdgcn_fdot2(a0, wreg[16+4*i+0], az,  false);
                    az  = __builtin_amdgcn_fdot2(a1, wreg[16+4*i+1], az,  false);
                    az  = __builtin_amdgcn_fdot2(a2, wreg[16+4*i+2], az,  false);
                    az  = __builtin_amdgcn_fdot2(a3, wreg[16+4*i+3], az,  false);
                    az  = __builtin_amdgcn_fdot2(c0, wreg[64+4*i+0], az,  false);
                    az  = __builtin_amdgcn_fdot2(c1, wreg[64+4*i+1], az,  false);
                    az  = __builtin_amdgcn_fdot2(c2, wreg[64+4*i+2], az,  false);
                    az  = __builtin_amdgcn_fdot2(c3, wreg[64+4*i+3], az,  false);
                    ain = __builtin_amdgcn_fdot2(a0, wreg[32+4*i+0], ain, false);
                    ain = __builtin_amdgcn_fdot2(a1, wreg[32+4*i+1], ain, false);
                    ain = __builtin_amdgcn_fdot2(a2, wreg[32+4*i+2], ain, false);
                    ain = __builtin_amdgcn_fdot2(a3, wreg[32+4*i+3], ain, false);
                    ahn = __builtin_amdgcn_fdot2(c0, wreg[80+4*i+0], ahn, false);
                    ahn = __builtin_amdgcn_fdot2(c1, wreg[80+4*i+1], ahn, false);
                    ahn = __builtin_amdgcn_fdot2(c2, wreg[80+4*i+2], ahn, false);
                    ahn = __builtin_amdgcn_fdot2(c3, wreg[80+4*i+3], ahn, false);
                }
                const float vr  = quad_reduce(ar)  + b_r;
                const float vz  = quad_reduce(az)  + b_z;
                const float vin = quad_reduce(ain) + b_in;
                const float vhn = quad_reduce(ahn) + b_hn;

                const float r  = sigf(vr);
                const float z  = sigf(vz);
                const float n  = tanh_fast(vin + r * vhn);
                const float hn = n + z * (hprev - n);
                hprev = hn;
                if (m == 0) {
                    sH1[cur ^ 1][j]    = (_Float16)hn;
                    sHo[ct & 1][twt][j] = hn;
                }
                // flush completed output chunk (k = 16*cp + 17)
                if ((k & (CH - 1)) == 1 && k >= CH + 1) {
                    const int cp  = (k >> 4) - 1;
                    const int idx = tid - 256;           // 512 lanes x float4
                    const float4 v = ((const float4*)&sHo[cp & 1][0][0])[idx];
                    ((float4*)(hb + (size_t)cp * CH * H))[idx] = v;
                }
            }
        }
        __syncthreads();
    }

    // epilogue: flush last chunk (cp = NCH-1)
    if (!isL0) {
        const int cp  = NCH - 1;
        const int idx = tid - 256;
        const float4 v = ((const float4*)&sHo[cp & 1][0][0])[idx];
        ((float4*)(hb + (size_t)cp * CH * H))[idx] = v;
    }
}

// ---------------------------------------------------------------------------
// MLP head, batched over all B*S rows. One wave per block; w1 row pinned in
// VGPRs (asm barrier — same sinking signature as the GRU weights).
// ---------------------------------------------------------------------------
__global__ __launch_bounds__(64, 2)
void head_kernel(const float* __restrict__ h1, const float* __restrict__ x,
                 const float* __restrict__ w1, const float* __restrict__ b1,
                 const float* __restrict__ w2, const float* __restrict__ b2,
                 float* __restrict__ inc, int rows_per_blk)
{
    __shared__ float sC[2][F];
    const int lane = threadIdx.x;

    float wr[F];
#pragma unroll
    for (int f = 0; f < F; f++) wr[f] = w1[lane * F + f];
    float b1v = b1[lane];
    float w2v = w2[lane];
    float b2v = b2[0];
#pragma unroll
    for (int f = 0; f < F; f++) pin_f(wr[f]);
    pin_f(b1v); pin_f(w2v); pin_f(b2v);

    const int row0 = blockIdx.x * rows_per_blk;
    {
        const int r = row0;
        sC[0][lane]      = h1[(size_t)r * H + lane];
        sC[0][64 + lane] = h1[(size_t)r * H + 64 + lane];
        if (lane < NI) sC[0][H + lane] = x[(size_t)r * NI + lane];
    }
    __syncthreads();

    for (int i = 0; i < rows_per_blk; i++) {
        const int row = row0 + i;
        const int cur = i & 1;
        const int nxt = cur ^ 1;

        float p0 = 0.f, p1 = 0.f, p2 = 0.f;
        if (i + 1 < rows_per_blk) {
            const int rn = row + 1;
            p0 = h1[(size_t)rn * H + lane];
            p1 = h1[(size_t)rn * H + 64 + lane];
            if (lane < NI) p2 = x[(size_t)rn * NI + lane];
        }

        float acc = b1v;
#pragma unroll
        for (int f = 0; f < F; f++) acc += sC[cur][f] * wr[f];

        if (i + 1 < rows_per_blk) {
            sC[nxt][lane]      = p0;
            sC[nxt][64 + lane] = p1;
            if (lane < NI) sC[nxt][H + lane] = p2;
        }

        float v = fmaxf(acc, 0.0f) * w2v;
#pragma unroll
        for (int off = 32; off > 0; off >>= 1) v += __shfl_xor(v, off, 64);

        if (lane == 0) inc[row] = tanh_fast(v + b2v) * 0.125f;
        __syncthreads();
    }
}

// ---------------------------------------------------------------------------
// Inclusive cumsum over S per batch + initial offset. One block per batch.
// ---------------------------------------------------------------------------
__global__ __launch_bounds__(256)
void cumsum_kernel(const float* __restrict__ inc, const float* __restrict__ init,
                   float* __restrict__ out)
{
    __shared__ float sW[4];
    const int b = blockIdx.x;
    const int tid = threadIdx.x;
    const int lane = tid & 63;
    const int wid = tid >> 6;

    const float* ib = inc + (size_t)b * S;
    float v[16];
#pragma unroll
    for (int i = 0; i < 16; i++) v[i] = ib[tid * 16 + i];

    float run = 0.f;
#pragma unroll
    for (int i = 0; i < 16; i++) { run += v[i]; v[i] = run; }

    float t = run;
#pragma unroll
    for (int off = 1; off < 64; off <<= 1) {
        float u = __shfl_up(t, off, 64);
        if (lane >= off) t += u;
    }
    const float excl = t - run;
    if (lane == 63) sW[wid] = t;
    __syncthreads();

    float wo = 0.f;
#pragma unroll
    for (int w = 0; w < 4; w++) if (w < wid) wo += sW[w];

    const float prefix = wo + excl + init[0];
    float* ob = out + (size_t)b * S;
#pragma unroll
    for (int i = 0; i < 16; i++) ob[tid * 16 + i] = prefix + v[i];
}

// ---------------------------------------------------------------------------
extern "C" void kernel_launch(void* const* d_in, const int* in_sizes, int n_in,
                              void* d_out, int out_size, void* d_ws, size_t ws_size,
                              hipStream_t stream)
{
    const float* x     = (const float*)d_in[0];
    const float* w_ih0 = (const float*)d_in[1];
    const float* w_hh0 = (const float*)d_in[2];
    const float* b_ih0 = (const float*)d_in[3];
    const float* b_hh0 = (const float*)d_in[4];
    const float* w_ih1 = (const float*)d_in[5];
    const float* w_hh1 = (const float*)d_in[6];
    const float* b_ih1 = (const float*)d_in[7];
    const float* b_hh1 = (const float*)d_in[8];
    const float* w1    = (const float*)d_in[9];
    const float* b1    = (const float*)d_in[10];
    const float* w2    = (const float*)d_in[11];
    const float* b2    = (const float*)d_in[12];
    const float* init  = (const float*)d_in[13];
    float* out = (float*)d_out;

    float* hbuf   = (float*)d_ws;                 // B*S*H fp32 = 134 MB (h1 only)
    float* incbuf = hbuf + (size_t)B * S * H;     // B*S fp32  = 1 MB

    hipLaunchKernelGGL(gru_fused, dim3(B), dim3(768), 0, stream,
                       x, w_ih0, w_hh0, b_ih0, b_hh0,
                       w_ih1, w_hh1, b_ih1, b_hh1, hbuf);
    hipLaunchKernelGGL(head_kernel, dim3((B * S) / 128), dim3(64), 0, stream,
                       hbuf, x, w1, b1, w2, b2, incbuf, 128);
    hipLaunchKernelGGL(cumsum_kernel, dim3(B), dim3(256), 0, stream,
                       incbuf, init, out);
}

// Round 9
// 4107.639 us; speedup vs baseline: 1.8646x; 1.1566x over previous
//
#include <hip/hip_runtime.h>
#include <cmath>

#define B 64
#define S 4096
#define NI 16
#define H 128
#define F 144   // H + NI
#define CH 16   // timesteps per output-staging chunk
#define NCH (S / CH)

typedef _Float16 h2   __attribute__((ext_vector_type(2)));
typedef _Float16 h4v  __attribute__((ext_vector_type(4)));
typedef _Float16 h8   __attribute__((ext_vector_type(8)));
typedef float    f4v  __attribute__((ext_vector_type(4)));

__device__ __forceinline__ float rcp_fast(float x) { return __builtin_amdgcn_rcpf(x); }
__device__ __forceinline__ float sigf(float x) {
    return rcp_fast(1.0f + __expf(-x));
}
// tanh(x) = 2*sigmoid(2x) - 1
__device__ __forceinline__ float tanh_fast(float x) {
    const float e = __expf(-2.0f * x);
    return fmaf(2.0f, rcp_fast(1.0f + e), -1.0f);
}
// all 4 lanes of each quad end with the 4-lane sum
__device__ __forceinline__ float quad_reduce(float v) {
    int t1 = __builtin_amdgcn_mov_dpp(__float_as_int(v), 0xB1, 0xf, 0xf, true); // xor 1
    v += __int_as_float(t1);
    int t2 = __builtin_amdgcn_mov_dpp(__float_as_int(v), 0x4E, 0xf, 0xf, true); // xor 2
    v += __int_as_float(t2);
    return v;
}
// both lanes of each pair end with the 2-lane sum
__device__ __forceinline__ float pair_reduce(float v) {
    int t1 = __builtin_amdgcn_mov_dpp(__float_as_int(v), 0xB1, 0xf, 0xf, true); // xor 1
    v += __int_as_float(t1);
    return v;
}
__device__ __forceinline__ h2 cvt2(float a, float b) {
    h2 r; r[0] = (_Float16)a; r[1] = (_Float16)b; return r;
}
// convert 8 consecutive fp32 -> 4 packed half2 regs
__device__ __forceinline__ void cvt8(const float* p, h2* w) {
    const float4 f0 = ((const float4*)p)[0];
    const float4 f1 = ((const float4*)p)[1];
    w[0] = cvt2(f0.x, f0.y); w[1] = cvt2(f0.z, f0.w);
    w[2] = cvt2(f1.x, f1.y); w[3] = cvt2(f1.z, f1.w);
}
// convert 8 consecutive fp32 -> h8
__device__ __forceinline__ h8 cvt8v(const float* p) {
    const float4 f0 = ((const float4*)p)[0];
    const float4 f1 = ((const float4*)p)[1];
    h8 r;
    r[0] = (_Float16)f0.x; r[1] = (_Float16)f0.y;
    r[2] = (_Float16)f0.z; r[3] = (_Float16)f0.w;
    r[4] = (_Float16)f1.x; r[5] = (_Float16)f1.y;
    r[6] = (_Float16)f1.z; r[7] = (_Float16)f1.w;
    return r;
}
__device__ __forceinline__ void pin_h2(h2& v) {
    int t = __builtin_bit_cast(int, v);
    asm volatile("" : "+v"(t));
    v = __builtin_bit_cast(h2, t);
}
__device__ __forceinline__ void pin_f(float& v) {
    asm volatile("" : "+v"(v));
}
__device__ __forceinline__ f4v mfma16(h8 a, h8 b, f4v c) {
    return __builtin_amdgcn_mfma_f32_16x16x32_f16(a, b, c, 0, 0, 0);
}

// ---------------------------------------------------------------------------
// Fused 2-layer GRU (round-8 body; h1 now stored fp16).
// 64 blocks x 768 threads. Waves 0-3: L0 (pair-split); waves 4-11: L1
// (quad-split). 1-step pipeline through fp16 LDS h0 state; h1 accumulated in
// fp16 LDS, flushed every CH steps.
// ---------------------------------------------------------------------------
__global__ __launch_bounds__(768, 3)
void gru_fused(const float* __restrict__ x,
               const float* __restrict__ w_ih0, const float* __restrict__ w_hh0,
               const float* __restrict__ b_ih0, const float* __restrict__ b_hh0,
               const float* __restrict__ w_ih1, const float* __restrict__ w_hh1,
               const float* __restrict__ b_ih1, const float* __restrict__ b_hh1,
               _Float16* __restrict__ h_out)
{
    __shared__ __align__(16) _Float16 sH0[2][H];      // h0 state ping-pong
    __shared__ __align__(16) _Float16 sH1[2][H];      // h1 state ping-pong
    __shared__ __align__(16) _Float16 sX[2][CH][NI];  // x chunks (fp16)
    __shared__ __align__(16) _Float16 sHo[2][CH][H];  // h1 out accum (fp16, 8 KB)

    const int b    = blockIdx.x;
    const int tid  = threadIdx.x;
    const bool isL0 = (tid < 256);

    h2 wreg[96];
    h2 wx[12];
    float b_r, b_z, b_in, b_hn;
    int j, m;

    if (isL0) {
        j = tid >> 1; m = tid & 1;
#pragma unroll
        for (int ii = 0; ii < 8; ii++) {
            cvt8(w_hh0 + (size_t)j * H         + 64 * m + 8 * ii, &wreg[4 * ii]);
            cvt8(w_hh0 + (size_t)(H + j) * H   + 64 * m + 8 * ii, &wreg[32 + 4 * ii]);
            cvt8(w_hh0 + (size_t)(2*H + j) * H + 64 * m + 8 * ii, &wreg[64 + 4 * ii]);
        }
        cvt8(w_ih0 + (size_t)j * NI         + 8 * m, &wx[0]);
        cvt8(w_ih0 + (size_t)(H + j) * NI   + 8 * m, &wx[4]);
        cvt8(w_ih0 + (size_t)(2*H + j) * NI + 8 * m, &wx[8]);
        b_r  = b_ih0[j]       + b_hh0[j];
        b_z  = b_ih0[H + j]   + b_hh0[H + j];
        b_in = b_ih0[2*H + j];
        b_hn = b_hh0[2*H + j];
    } else {
        const int tid1 = tid - 256;
        j = tid1 >> 2; m = tid1 & 3;
#pragma unroll
        for (int i = 0; i < 4; i++) {
            const int f = (i + m) & 3;
            const int o = 32 * m + 8 * f;
            cvt8(w_ih1 + (size_t)j * H         + o, &wreg[ 0 + 4 * i]);
            cvt8(w_ih1 + (size_t)(H + j) * H   + o, &wreg[16 + 4 * i]);
            cvt8(w_ih1 + (size_t)(2*H + j) * H + o, &wreg[32 + 4 * i]);
            cvt8(w_hh1 + (size_t)j * H         + o, &wreg[48 + 4 * i]);
            cvt8(w_hh1 + (size_t)(H + j) * H   + o, &wreg[64 + 4 * i]);
            cvt8(w_hh1 + (size_t)(2*H + j) * H + o, &wreg[80 + 4 * i]);
        }
        b_r  = b_ih1[j]       + b_hh1[j];
        b_z  = b_ih1[H + j]   + b_hh1[H + j];
        b_in = b_ih1[2*H + j];
        b_hn = b_hh1[2*H + j];
    }
#pragma unroll
    for (int i = 0; i < 96; i++) pin_h2(wreg[i]);
#pragma unroll
    for (int i = 0; i < 12; i++) pin_h2(wx[i]);
    pin_f(b_r); pin_f(b_z); pin_f(b_in); pin_f(b_hn);

    const float* xb = x + (size_t)b * S * NI;
    _Float16*    hb = h_out + (size_t)b * S * H;

    float4 xreg = {0.f, 0.f, 0.f, 0.f};
    if (tid < H) { sH0[0][tid] = (_Float16)0.0f; sH1[1][tid] = (_Float16)0.0f; }
    if (tid < 64) {
        const float4 v = ((const float4*)xb)[tid];
        h4v p; p[0] = (_Float16)v.x; p[1] = (_Float16)v.y;
               p[2] = (_Float16)v.z; p[3] = (_Float16)v.w;
        ((h4v*)&sX[0][0][0])[tid] = p;
        xreg = ((const float4*)(xb + CH * NI))[tid];
    }
    float hprev = 0.0f;
    __syncthreads();

    for (int k = 0; k <= S; k++) {
        const int cur = k & 1;

        if (isL0) {
            if (k < S) {
                const int c0  = k >> 4;
                const int tw0 = k & (CH - 1);

                if (tw0 == 0 && tid < 64) {
                    const int cn = c0 + 1;
                    if (cn < NCH) {
                        h4v p; p[0] = (_Float16)xreg.x; p[1] = (_Float16)xreg.y;
                               p[2] = (_Float16)xreg.z; p[3] = (_Float16)xreg.w;
                        ((h4v*)&sX[cn & 1][0][0])[tid] = p;
                        if (cn + 1 < NCH)
                            xreg = ((const float4*)(xb + (size_t)(cn + 1) * CH * NI))[tid];
                    }
                }

                const float4* hv = (const float4*)&sH0[cur][0];
                float ar = 0.f, az = 0.f, ahn = 0.f;
#pragma unroll
                for (int i = 0; i < 8; i++) {
                    const float4 q = hv[8 * m + i];
                    const h2 p0 = __builtin_bit_cast(h2, q.x);
                    const h2 p1 = __builtin_bit_cast(h2, q.y);
                    const h2 p2 = __builtin_bit_cast(h2, q.z);
                    const h2 p3 = __builtin_bit_cast(h2, q.w);
                    ar  = __builtin_amdgcn_fdot2(p0, wreg[4*i+0],    ar,  false);
                    ar  = __builtin_amdgcn_fdot2(p1, wreg[4*i+1],    ar,  false);
                    ar  = __builtin_amdgcn_fdot2(p2, wreg[4*i+2],    ar,  false);
                    ar  = __builtin_amdgcn_fdot2(p3, wreg[4*i+3],    ar,  false);
                    az  = __builtin_amdgcn_fdot2(p0, wreg[32+4*i+0], az,  false);
                    az  = __builtin_amdgcn_fdot2(p1, wreg[32+4*i+1], az,  false);
                    az  = __builtin_amdgcn_fdot2(p2, wreg[32+4*i+2], az,  false);
                    az  = __builtin_amdgcn_fdot2(p3, wreg[32+4*i+3], az,  false);
                    ahn = __builtin_amdgcn_fdot2(p0, wreg[64+4*i+0], ahn, false);
                    ahn = __builtin_amdgcn_fdot2(p1, wreg[64+4*i+1], ahn, false);
                    ahn = __builtin_amdgcn_fdot2(p2, wreg[64+4*i+2], ahn, false);
                    ahn = __builtin_amdgcn_fdot2(p3, wreg[64+4*i+3], ahn, false);
                }
                const float4 xq = *(const float4*)&sX[c0 & 1][tw0][8 * m];
                const h2 x0 = __builtin_bit_cast(h2, xq.x);
                const h2 x1 = __builtin_bit_cast(h2, xq.y);
                const h2 x2 = __builtin_bit_cast(h2, xq.z);
                const h2 x3 = __builtin_bit_cast(h2, xq.w);
                float ain = 0.f;
                ar  = __builtin_amdgcn_fdot2(x0, wx[0],  ar,  false);
                ar  = __builtin_amdgcn_fdot2(x1, wx[1],  ar,  false);
                ar  = __builtin_amdgcn_fdot2(x2, wx[2],  ar,  false);
                ar  = __builtin_amdgcn_fdot2(x3, wx[3],  ar,  false);
                az  = __builtin_amdgcn_fdot2(x0, wx[4],  az,  false);
                az  = __builtin_amdgcn_fdot2(x1, wx[5],  az,  false);
                az  = __builtin_amdgcn_fdot2(x2, wx[6],  az,  false);
                az  = __builtin_amdgcn_fdot2(x3, wx[7],  az,  false);
                ain = __builtin_amdgcn_fdot2(x0, wx[8],  ain, false);
                ain = __builtin_amdgcn_fdot2(x1, wx[9],  ain, false);
                ain = __builtin_amdgcn_fdot2(x2, wx[10], ain, false);
                ain = __builtin_amdgcn_fdot2(x3, wx[11], ain, false);

                const float vr  = pair_reduce(ar)  + b_r;
                const float vz  = pair_reduce(az)  + b_z;
                const float vhn = pair_reduce(ahn) + b_hn;
                const float vin = pair_reduce(ain) + b_in;

                const float r  = sigf(vr);
                const float z  = sigf(vz);
                const float n  = tanh_fast(vin + r * vhn);
                const float hn = n + z * (hprev - n);
                hprev = hn;
                if (m == 0) sH0[cur ^ 1][j] = (_Float16)hn;
            }
        } else {
            if (k >= 1) {
                const int t   = k - 1;
                const int ct  = t >> 4;
                const int twt = t & (CH - 1);

                const float4* A4 = (const float4*)&sH0[cur][0];   // h0[t]
                const float4* C4 = (const float4*)&sH1[cur][0];   // h1[t-1]
                float ar = 0.f, az = 0.f, ain = 0.f, ahn = 0.f;
#pragma unroll
                for (int i = 0; i < 4; i++) {
                    const int f = (i + m) & 3;                    // addr stagger
                    const float4 qa = A4[4 * m + f];
                    const float4 qc = C4[4 * m + f];
                    const h2 a0 = __builtin_bit_cast(h2, qa.x);
                    const h2 a1 = __builtin_bit_cast(h2, qa.y);
                    const h2 a2 = __builtin_bit_cast(h2, qa.z);
                    const h2 a3 = __builtin_bit_cast(h2, qa.w);
                    const h2 c0 = __builtin_bit_cast(h2, qc.x);
                    const h2 c1 = __builtin_bit_cast(h2, qc.y);
                    const h2 c2 = __builtin_bit_cast(h2, qc.z);
                    const h2 c3 = __builtin_bit_cast(h2, qc.w);
                    ar  = __builtin_amdgcn_fdot2(a0, wreg[ 0+4*i+0], ar,  false);
                    ar  = __builtin_amdgcn_fdot2(a1, wreg[ 0+4*i+1], ar,  false);
                    ar  = __builtin_amdgcn_fdot2(a2, wreg[ 0+4*i+2], ar,  false);
                    ar  = __builtin_amdgcn_fdot2(a3, wreg[ 0+4*i+3], ar,  false);
                    ar  = __builtin_amdgcn_fdot2(c0, wreg[48+4*i+0], ar,  false);
                    ar  = __builtin_amdgcn_fdot2(c1, wreg[48+4*i+1], ar,  false);
                    ar  = __builtin_amdgcn_fdot2(c2, wreg[48+4*i+2], ar,  false);
                    ar  = __builtin_amdgcn_fdot2(c3, wreg[48+4*i+3], ar,  false);
                    az  = __builtin_amdgcn_fdot2(a0, wreg[16+4*i+0], az,  false);
                    az  = __builtin_amdgcn_fdot2(a1, wreg[16+4*i+1], az,  false);
                    az  = __builtin_amdgcn_fdot2(a2, wreg[16+4*i+2], az,  false);
                    az  = __builtin_amdgcn_fdot2(a3, wreg[16+4*i+3], az,  false);
                    az  = __builtin_amdgcn_fdot2(c0, wreg[64+4*i+0], az,  false);
                    az  = __builtin_amdgcn_fdot2(c1, wreg[64+4*i+1], az,  false);
                    az  = __builtin_amdgcn_fdot2(c2, wreg[64+4*i+2], az,  false);
                    az  = __builtin_amdgcn_fdot2(c3, wreg[64+4*i+3], az,  false);
                    ain = __builtin_amdgcn_fdot2(a0, wreg[32+4*i+0], ain, false);
                    ain = __builtin_amdgcn_fdot2(a1, wreg[32+4*i+1], ain, false);
                    ain = __builtin_amdgcn_fdot2(a2, wreg[32+4*i+2], ain, false);
                    ain = __builtin_amdgcn_fdot2(a3, wreg[32+4*i+3], ain, false);
                    ahn = __builtin_amdgcn_fdot2(c0, wreg[80+4*i+0], ahn, false);
                    ahn = __builtin_amdgcn_fdot2(c1, wreg[80+4*i+1], ahn, false);
                    ahn = __builtin_amdgcn_fdot2(c2, wreg[80+4*i+2], ahn, false);
                    ahn = __builtin_amdgcn_fdot2(c3, wreg[80+4*i+3], ahn, false);
                }
                const float vr  = quad_reduce(ar)  + b_r;
                const float vz  = quad_reduce(az)  + b_z;
                const float vin = quad_reduce(ain) + b_in;
                const float vhn = quad_reduce(ahn) + b_hn;

                const float r  = sigf(vr);
                const float z  = sigf(vz);
                const float n  = tanh_fast(vin + r * vhn);
                const float hn = n + z * (hprev - n);
                hprev = hn;
                if (m == 0) {
                    sH1[cur ^ 1][j]     = (_Float16)hn;
                    sHo[ct & 1][twt][j] = (_Float16)hn;
                }
                // flush completed output chunk (fp16: 2048 halves, 512 x 8B)
                if ((k & (CH - 1)) == 1 && k >= CH + 1) {
                    const int cp  = (k >> 4) - 1;
                    const int idx = tid - 256;
                    const uint2 v = ((const uint2*)&sHo[cp & 1][0][0])[idx];
                    ((uint2*)(hb + (size_t)cp * CH * H))[idx] = v;
                }
            }
        }
        __syncthreads();
    }

    if (!isL0) {
        const int cp  = NCH - 1;
        const int idx = tid - 256;
        const uint2 v = ((const uint2*)&sHo[cp & 1][0][0])[idx];
        ((uint2*)(hb + (size_t)cp * CH * H))[idx] = v;
    }
}

// ---------------------------------------------------------------------------
// MFMA MLP head. 512 blocks x 256 threads (4 independent waves, no barriers).
// Each wave: 8 tiles of 16 rows. Per tile: A = [h1|x] (16x160 fp16, K padded),
// B = w1 as 4 N-tiles x 5 K-chunks of stationary fragments (80 VGPR).
// C-layout epilogue: +b1, relu, x w2, 4-step shuffle reduce over n, tanh,
// float4 store of 4 consecutive rows per writer lane.
// ---------------------------------------------------------------------------
__global__ __launch_bounds__(256, 2)
void head_mfma(const _Float16* __restrict__ h1, const float* __restrict__ x,
               const float* __restrict__ w1, const float* __restrict__ b1,
               const float* __restrict__ w2, const float* __restrict__ b2,
               float* __restrict__ inc)
{
    const int wave = threadIdx.x >> 6;
    const int lane = threadIdx.x & 63;
    const int nl   = lane & 15;          // n within tile / A row m
    const int q    = lane >> 4;          // k-group / C row group

    // stationary B fragments: B[k][n] = w1[n][k], n = 16t + nl, k = 32c + 8q + i
    h8 Bf[4][5];
    float b1v[4], w2v[4];
#pragma unroll
    for (int t = 0; t < 4; t++) {
        const int n = 16 * t + nl;
        const float* wr = w1 + (size_t)n * F;
#pragma unroll
        for (int c = 0; c < 4; c++)
            Bf[t][c] = cvt8v(wr + 32 * c + 8 * q);
        if (q < 2) Bf[t][4] = cvt8v(wr + 128 + 8 * q);
        else { h8 z = {};
               Bf[t][4] = z; }
        b1v[t] = b1[n];
        w2v[t] = w2[n];
    }
    const float b2v = b2[0];

    const int gw = blockIdx.x * 4 + wave;    // 2048 waves x 8 tiles x 16 rows

    for (int it = 0; it < 8; it++) {
        const int row0 = (gw * 8 + it) * 16;
        const int rm   = row0 + nl;          // this lane's A row

        // A fragments: chunks 0..3 from h1 (fp16), chunk 4 = x padded
        const _Float16* hp = h1 + (size_t)rm * H;
        h8 A0 = *(const h8*)(hp + 8 * q);
        h8 A1 = *(const h8*)(hp + 32 + 8 * q);
        h8 A2 = *(const h8*)(hp + 64 + 8 * q);
        h8 A3 = *(const h8*)(hp + 96 + 8 * q);
        h8 A4;
        if (q < 2) A4 = cvt8v(x + (size_t)rm * NI + 8 * q);
        else { h8 z = {}; A4 = z; }

        f4v acc0 = {0.f,0.f,0.f,0.f}, acc1 = {0.f,0.f,0.f,0.f};
        f4v acc2 = {0.f,0.f,0.f,0.f}, acc3 = {0.f,0.f,0.f,0.f};
        acc0 = mfma16(A0, Bf[0][0], acc0); acc1 = mfma16(A0, Bf[1][0], acc1);
        acc2 = mfma16(A0, Bf[2][0], acc2); acc3 = mfma16(A0, Bf[3][0], acc3);
        acc0 = mfma16(A1, Bf[0][1], acc0); acc1 = mfma16(A1, Bf[1][1], acc1);
        acc2 = mfma16(A1, Bf[2][1], acc2); acc3 = mfma16(A1, Bf[3][1], acc3);
        acc0 = mfma16(A2, Bf[0][2], acc0); acc1 = mfma16(A2, Bf[1][2], acc1);
        acc2 = mfma16(A2, Bf[2][2], acc2); acc3 = mfma16(A2, Bf[3][2], acc3);
        acc0 = mfma16(A3, Bf[0][3], acc0); acc1 = mfma16(A3, Bf[1][3], acc1);
        acc2 = mfma16(A3, Bf[2][3], acc2); acc3 = mfma16(A3, Bf[3][3], acc3);
        acc0 = mfma16(A4, Bf[0][4], acc0); acc1 = mfma16(A4, Bf[1][4], acc1);
        acc2 = mfma16(A4, Bf[2][4], acc2); acc3 = mfma16(A4, Bf[3][4], acc3);

        // epilogue: relu(acc + b1) * w2, sum over this lane's 4 n's per row r
        float rs[4];
#pragma unroll
        for (int r = 0; r < 4; r++) {
            rs[r] = fmaxf(acc0[r] + b1v[0], 0.f) * w2v[0]
                  + fmaxf(acc1[r] + b1v[1], 0.f) * w2v[1]
                  + fmaxf(acc2[r] + b1v[2], 0.f) * w2v[2]
                  + fmaxf(acc3[r] + b1v[3], 0.f) * w2v[3];
        }
        // reduce across the 16 lanes of the same q-group (different n)
#pragma unroll
        for (int off = 1; off < 16; off <<= 1) {
#pragma unroll
            for (int r = 0; r < 4; r++)
                rs[r] += __shfl_xor(rs[r], off, 64);
        }
        if (nl == 0) {
            float4 o;
            o.x = tanh_fast(rs[0] + b2v) * 0.125f;
            o.y = tanh_fast(rs[1] + b2v) * 0.125f;
            o.z = tanh_fast(rs[2] + b2v) * 0.125f;
            o.w = tanh_fast(rs[3] + b2v) * 0.125f;
            *(float4*)(inc + row0 + 4 * q) = o;   // rows row0+4q .. +3
        }
    }
}

// ---------------------------------------------------------------------------
// Inclusive cumsum over S per batch + initial offset. One block per batch.
// ---------------------------------------------------------------------------
__global__ __launch_bounds__(256)
void cumsum_kernel(const float* __restrict__ inc, const float* __restrict__ init,
                   float* __restrict__ out)
{
    __shared__ float sW[4];
    const int b = blockIdx.x;
    const int tid = threadIdx.x;
    const int lane = tid & 63;
    const int wid = tid >> 6;

    const float* ib = inc + (size_t)b * S;
    float v[16];
#pragma unroll
    for (int i = 0; i < 16; i++) v[i] = ib[tid * 16 + i];

    float run = 0.f;
#pragma unroll
    for (int i = 0; i < 16; i++) { run += v[i]; v[i] = run; }

    float t = run;
#pragma unroll
    for (int off = 1; off < 64; off <<= 1) {
        float u = __shfl_up(t, off, 64);
        if (lane >= off) t += u;
    }
    const float excl = t - run;
    if (lane == 63) sW[wid] = t;
    __syncthreads();

    float wo = 0.f;
#pragma unroll
    for (int w = 0; w < 4; w++) if (w < wid) wo += sW[w];

    const float prefix = wo + excl + init[0];
    float* ob = out + (size_t)b * S;
#pragma unroll
    for (int i = 0; i < 16; i++) ob[tid * 16 + i] = prefix + v[i];
}

// ---------------------------------------------------------------------------
extern "C" void kernel_launch(void* const* d_in, const int* in_sizes, int n_in,
                              void* d_out, int out_size, void* d_ws, size_t ws_size,
                              hipStream_t stream)
{
    const float* x     = (const float*)d_in[0];
    const float* w_ih0 = (const float*)d_in[1];
    const float* w_hh0 = (const float*)d_in[2];
    const float* b_ih0 = (const float*)d_in[3];
    const float* b_hh0 = (const float*)d_in[4];
    const float* w_ih1 = (const float*)d_in[5];
    const float* w_hh1 = (const float*)d_in[6];
    const float* b_ih1 = (const float*)d_in[7];
    const float* b_hh1 = (const float*)d_in[8];
    const float* w1    = (const float*)d_in[9];
    const float* b1    = (const float*)d_in[10];
    const float* w2    = (const float*)d_in[11];
    const float* b2    = (const float*)d_in[12];
    const float* init  = (const float*)d_in[13];
    float* out = (float*)d_out;

    _Float16* hbuf = (_Float16*)d_ws;                               // 67 MB fp16
    float* incbuf  = (float*)((char*)d_ws + (size_t)B * S * H * 2); // 1 MB

    hipLaunchKernelGGL(gru_fused, dim3(B), dim3(768), 0, stream,
                       x, w_ih0, w_hh0, b_ih0, b_hh0,
                       w_ih1, w_hh1, b_ih1, b_hh1, hbuf);
    hipLaunchKernelGGL(head_mfma, dim3(512), dim3(256), 0, stream,
                       hbuf, x, w1, b1, w2, b2, incbuf);
    hipLaunchKernelGGL(cumsum_kernel, dim3(B), dim3(256), 0, stream,
                       incbuf, init, out);
}